// Round 3
// baseline (338.113 us; speedup 1.0000x reference)
//
#include <hip/hip_runtime.h>
#include <stdint.h>

#define HH 4096
#define WW 4096
#define NPIX (HH * WW)
#define NBINS 8192
#define NFRAG 64
#define FRAG_PIX (512 * 512)   // 2^18
#define WPR 64                 // u64 words per row (4096/64)
#define NWORDS (HH * WPR)      // 262144
#define CAP 4096               // per-fragment critical-band capacity

// Reference stop conditions (integer-exact):
//   phase0 stop: cnt >= 31458 <=> th < V_HI,  V_HI = v_sorted[230686]
//   phase1 stop: cnt <= 20971 <=> th >= V_LO, V_LO = v_sorted[241172]
#define RANK_HI 230686u
#define RANK_LO 241172u

typedef unsigned long long u64;

__device__ __forceinline__ int frag_of(int py, int px) {
  return ((py >> 9) << 3) + (px >> 9);
}

__device__ __forceinline__ int bin_of(float v) {
  int b = (int)(v * 8192.0f);   // monotone f32 map
  if (b < 0) b = 0;
  if (b > NBINS - 1) b = NBINS - 1;
  return b;
}

// spread 16 bits so bit i lands at position 4i
__device__ __forceinline__ u64 spread4(u64 x) {
  x &= 0xFFFFull;
  x = (x | (x << 24)) & 0x000000FF000000FFull;
  x = (x | (x << 12)) & 0x000F000F000F000Full;
  x = (x | (x << 6))  & 0x0303030303030303ull;
  x = (x | (x << 3))  & 0x1111111111111111ull;
  return x;
}

// ---------------------------------------------------------------------------
// VERIFIED bit-exact blur tree (numpy pairwise_sum n=25 over materialized
// (windows*k), row-major taps, OOB -> exact 0). DO NOT TOUCH.
// ---------------------------------------------------------------------------
__device__ __forceinline__ float blur_tree(const float rowbuf[5][8], int e) {
  const float K = (float)(1.0 / 25.0);
  float p[25];
#pragma unroll
  for (int i = 0; i < 25; ++i) {
    p[i] = __fmul_rn(rowbuf[i / 5][e + (i % 5)], K);
  }
  float r0 = __fadd_rn(__fadd_rn(p[0], p[8]),  p[16]);
  float r1 = __fadd_rn(__fadd_rn(p[1], p[9]),  p[17]);
  float r2 = __fadd_rn(__fadd_rn(p[2], p[10]), p[18]);
  float r3 = __fadd_rn(__fadd_rn(p[3], p[11]), p[19]);
  float r4 = __fadd_rn(__fadd_rn(p[4], p[12]), p[20]);
  float r5 = __fadd_rn(__fadd_rn(p[5], p[13]), p[21]);
  float r6 = __fadd_rn(__fadd_rn(p[6], p[14]), p[22]);
  float r7 = __fadd_rn(__fadd_rn(p[7], p[15]), p[23]);
  float res = __fadd_rn(
      __fadd_rn(__fadd_rn(r0, r1), __fadd_rn(r2, r3)),
      __fadd_rn(__fadd_rn(r4, r5), __fadd_rn(r6, r7)));
  return __fadd_rn(res, p[24]);
}

// ---------------------------------------------------------------------------
// 1) FUSED blur + per-fragment LDS histogram.
//    4x4 output patch per thread: 8 rows x 8 cols of input in registers,
//    24 vector loads -> 16 outputs, 4 blur trees of ILP between stalls.
// ---------------------------------------------------------------------------
__global__ void __launch_bounds__(512)
blur_hist_kernel(const float* __restrict__ x,
                 float* __restrict__ out,
                 uint32_t* __restrict__ hist) {
  __shared__ uint32_t lh[NBINS];
  int tid = threadIdx.x;
  for (int i = tid; i < NBINS; i += 512) lh[i] = 0;
  __syncthreads();
  int f = blockIdx.x >> 4;
  int s = blockIdx.x & 15;
  int row0 = (f >> 3) * 512 + s * 32;
  int col0 = (f & 7) * 512;
  // 8 patch-rows x 128 patch-cols per 32x512 slice; 512 threads -> 2 iters
  for (int it = tid; it < 8 * 128; it += 512) {
    int pr = it >> 7;          // patch row 0..7
    int c4 = it & 127;         // patch col 0..127
    int py = row0 + pr * 4;
    int px = col0 + c4 * 4;
    float rb[8][8];
    bool interior = (px >= 2) && (px + 5 < WW);
#pragma unroll
    for (int r = 0; r < 8; ++r) {
      int yy = py - 2 + r;
      if ((unsigned)yy >= (unsigned)HH) {
#pragma unroll
        for (int j = 0; j < 8; ++j) rb[r][j] = 0.0f;
      } else if (interior) {
        const float* rp = x + (size_t)yy * WW + px;
        float2 L = *(const float2*)(rp - 2);
        float4 M = *(const float4*)(rp);
        float2 R = *(const float2*)(rp + 4);
        rb[r][0] = L.x; rb[r][1] = L.y;
        rb[r][2] = M.x; rb[r][3] = M.y;
        rb[r][4] = M.z; rb[r][5] = M.w;
        rb[r][6] = R.x; rb[r][7] = R.y;
      } else {
#pragma unroll
        for (int j = 0; j < 8; ++j) {
          int xx = px - 2 + j;
          rb[r][j] = ((unsigned)xx < (unsigned)WW) ? x[(size_t)yy * WW + xx] : 0.0f;
        }
      }
    }
#pragma unroll
    for (int orow = 0; orow < 4; ++orow) {
      float4 res;
      res.x = blur_tree(rb + orow, 0);
      res.y = blur_tree(rb + orow, 1);
      res.z = blur_tree(rb + orow, 2);
      res.w = blur_tree(rb + orow, 3);
      *(float4*)(out + (size_t)(py + orow) * WW + px) = res;
      atomicAdd(&lh[bin_of(res.x)], 1u);
      atomicAdd(&lh[bin_of(res.y)], 1u);
      atomicAdd(&lh[bin_of(res.z)], 1u);
      atomicAdd(&lh[bin_of(res.w)], 1u);
    }
  }
  __syncthreads();
  uint32_t* hf = hist + f * NBINS;
  for (int i = tid; i < NBINS; i += 512) {
    uint32_t c = lh[i];
    if (c) atomicAdd(&hf[i], c);
  }
}

// ---------------------------------------------------------------------------
// 2) find critical buckets + local ranks. bins4[f] = (bhi, blo, khi, klo).
// ---------------------------------------------------------------------------
__global__ void findcrit_kernel(const uint32_t* __restrict__ hist,
                                int4* __restrict__ bins4) {
  __shared__ uint32_t segsum[256];
  __shared__ uint32_t segoff[256];
  __shared__ int4 result;
  int f = blockIdx.x;
  int tid = threadIdx.x;
  const uint32_t* hf = hist + f * NBINS;
  int base = tid * 32;
  uint32_t h32[32];
  uint32_t s = 0;
  for (int i = 0; i < 32; ++i) { h32[i] = hf[base + i]; s += h32[i]; }
  segsum[tid] = s;
  __syncthreads();
  if (tid == 0) {
    uint32_t a = 0;
    for (int i = 0; i < 256; ++i) { segoff[i] = a; a += segsum[i]; }
  }
  __syncthreads();
  uint32_t st = segoff[tid];
  uint32_t en = st + segsum[tid];
  if (st <= RANK_HI && RANK_HI < en) {
    uint32_t a = st;
    for (int i = 0; i < 32; ++i) {
      uint32_t nx = a + h32[i];
      if (RANK_HI < nx) { result.x = base + i; result.z = (int)(RANK_HI - a); break; }
      a = nx;
    }
  }
  if (st <= RANK_LO && RANK_LO < en) {
    uint32_t a = st;
    for (int i = 0; i < 32; ++i) {
      uint32_t nx = a + h32[i];
      if (RANK_LO < nx) { result.y = base + i; result.w = (int)(RANK_LO - a); break; }
      a = nx;
    }
  }
  __syncthreads();
  if (tid == 0) bins4[f] = result;
}

// ---------------------------------------------------------------------------
// 3) gather critical-bucket values — 32 px/thread, 8 float4 loads with a
//    forced join (empty asm consuming one lane of each vector) so all 8
//    loads are in flight before any wait. Fixes the VGPR=16 load-sinking
//    pathology (each load serialized at full memory latency).
// ---------------------------------------------------------------------------
__global__ void __launch_bounds__(256)
gather_kernel(const float* __restrict__ blur,
              const int4* __restrict__ bins4,
              float* __restrict__ band,
              uint32_t* __restrict__ bandcnt) {
  const int T = NPIX / 32;   // 524,288 threads, 8 float4-slices each
  int t = blockIdx.x * blockDim.x + threadIdx.x;
  float4 v[8];
#pragma unroll
  for (int k = 0; k < 8; ++k) {
    v[k] = *(const float4*)(blur + (size_t)(t + k * T) * 4);
  }
  // join: force all 8 loads issued before first use
  asm volatile("" :: "v"(v[0].x), "v"(v[1].x), "v"(v[2].x), "v"(v[3].x),
                     "v"(v[4].x), "v"(v[5].x), "v"(v[6].x), "v"(v[7].x));
#pragma unroll
  for (int k = 0; k < 8; ++k) {
    int p0 = (t + k * T) * 4;
    int f = frag_of(p0 >> 12, p0 & (WW - 1));
    int4 info = bins4[f];
    float vv[4] = {v[k].x, v[k].y, v[k].z, v[k].w};
#pragma unroll
    for (int e = 0; e < 4; ++e) {
      int b = bin_of(vv[e]);
      if (b == info.x || b == info.y) {
        uint32_t pos = atomicAdd(&bandcnt[f], 1u);
        if (pos < CAP) band[(size_t)f * CAP + pos] = vv[e];
      }
    }
  }
}

// ---------------------------------------------------------------------------
// 4) exact order-statistic selection within the critical buckets
// ---------------------------------------------------------------------------
__global__ void select_kernel(const float* __restrict__ band,
                              const uint32_t* __restrict__ bandcnt,
                              const int4* __restrict__ bins4,
                              float2* __restrict__ vhl) {
  __shared__ float wv[CAP];
  __shared__ float res[2];
  int f = blockIdx.x;
  int tid = threadIdx.x;
  int n = (int)bandcnt[f];
  if (n > CAP) n = CAP;
  for (int i = tid; i < n; i += 256) wv[i] = band[(size_t)f * CAP + i];
  __syncthreads();
  int4 info = bins4[f];
#pragma unroll
  for (int sel = 0; sel < 2; ++sel) {
    int tb = sel ? info.y : info.x;
    int k  = sel ? info.w : info.z;
    for (int i = tid; i < n; i += 256) {
      float w = wv[i];
      if (bin_of(w) != tb) continue;
      int less = 0, leq = 0;
      for (int j = 0; j < n; ++j) {
        float u = wv[j];
        if (bin_of(u) == tb) {
          less += (u < w) ? 1 : 0;
          leq  += (u <= w) ? 1 : 0;
        }
      }
      if (less <= k && k < leq) res[sel] = w;   // unique value; benign race
    }
  }
  __syncthreads();
  if (tid == 0) vhl[f] = make_float2(res[0], res[1]);
}

// ---------------------------------------------------------------------------
// 5) threshold walk — branchless predicated steps (16 per exit check).
//    Each conditional step is EXACTLY the reference's while-iteration:
//    taken  -> th = __fadd_rn(th, ±step) ; not-taken -> no-op.
// ---------------------------------------------------------------------------
__global__ void walk_kernel(const float2* __restrict__ vhl, float* __restrict__ th_out) {
  int lane = threadIdx.x;
  float2 mine = vhl[lane];   // lane f holds fragment f's (V_HI, V_LO)
  float th = 0.5f;           // TH1_INIT
  for (int f = 0; f < NFRAG; ++f) {
    float VH = __shfl(mine.x, f);
    float VL = __shfl(mine.y, f);
    // phase 0: while th >= VH: th -= 0.0005
    while (th >= VH) {
#pragma unroll
      for (int i = 0; i < 16; ++i) {
        float t2 = __fadd_rn(th, -0.0005f);
        th = (th >= VH) ? t2 : th;
      }
    }
    // phase 1: while th < VL: th += 0.0005
    while (th < VL) {
#pragma unroll
      for (int i = 0; i < 16; ++i) {
        float t2 = __fadd_rn(th, 0.0005f);
        th = (th < VL) ? t2 : th;
      }
    }
    if (lane == 0) th_out[f] = th;
  }
}

// ---------------------------------------------------------------------------
// 6) mask + bit-pack — 32 px/thread, 8 float4 loads with forced join,
//    ballot interleave. Same word mapping as before: wave-base group
//    (g - lane) stays 64-aligned, T multiple of 16 -> exact same output.
// ---------------------------------------------------------------------------
__global__ void __launch_bounds__(256)
mask_pack_kernel(const float* __restrict__ blur,
                 const float* __restrict__ th,
                 u64* __restrict__ pk) {
  const int T = NPIX / 32;   // 524,288 threads, 8 groups each
  int t = blockIdx.x * blockDim.x + threadIdx.x;
  float4 v[8];
#pragma unroll
  for (int k = 0; k < 8; ++k) {
    v[k] = *(const float4*)(blur + (size_t)(t + k * T) * 4);
  }
  asm volatile("" :: "v"(v[0].x), "v"(v[1].x), "v"(v[2].x), "v"(v[3].x),
                     "v"(v[4].x), "v"(v[5].x), "v"(v[6].x), "v"(v[7].x));
  int lane = threadIdx.x & 63;
#pragma unroll
  for (int k = 0; k < 8; ++k) {
    int g = t + k * T;           // 4-px group index
    int p0 = g * 4;
    float tf = th[frag_of(p0 >> 12, p0 & (WW - 1))];
    u64 b0 = __ballot(v[k].x > tf);
    u64 b1 = __ballot(v[k].y > tf);
    u64 b2 = __ballot(v[k].z > tf);
    u64 b3 = __ballot(v[k].w > tf);
    if ((lane & 15) == 0) {
      int sh = lane;             // 0,16,32,48
      u64 w = spread4(b0 >> sh) | (spread4(b1 >> sh) << 1)
            | (spread4(b2 >> sh) << 2) | (spread4(b3 >> sh) << 3);
      int base_word = ((g - lane) * 4) >> 6;
      pk[base_word + (lane >> 4)] = w;
    }
  }
}

// ---------------------------------------------------------------------------
// 7) fused dilate (H+V) on packed bits; OOB = 0 (clipped window).
// ---------------------------------------------------------------------------
__global__ void dilate_kernel(const u64* __restrict__ in, u64* __restrict__ out) {
  __shared__ u64 hm[68][16];
  int bx = blockIdx.x & 3;
  int by = blockIdx.x >> 2;
  int r0 = by * 64, c0 = bx * 16;
  int tid = threadIdx.x;
  for (int it = tid; it < 68 * 16; it += 256) {
    int rr = it >> 4;
    int cc = it & 15;
    int gy = r0 - 2 + rr;
    int gx = c0 + cc;
    u64 m = 0, l = 0, r = 0;
    if ((unsigned)gy < (unsigned)HH) {
      m = in[gy * WPR + gx];
      l = (gx > 0) ? in[gy * WPR + gx - 1] : 0ull;
      r = (gx < WPR - 1) ? in[gy * WPR + gx + 1] : 0ull;
    }
    hm[rr][cc] = m | (m << 1) | (m << 2) | (m >> 1) | (m >> 2)
                   | (l >> 62) | (l >> 63) | (r << 62) | (r << 63);
  }
  __syncthreads();
  for (int it = tid; it < 64 * 16; it += 256) {
    int rr = it >> 4;
    int cc = it & 15;
    u64 v = hm[rr][cc] | hm[rr + 1][cc] | hm[rr + 2][cc] | hm[rr + 3][cc] | hm[rr + 4][cc];
    out[(r0 + rr) * WPR + c0 + cc] = v;
  }
}

// ---------------------------------------------------------------------------
// 8) fused erode (De Morgan) + unpack to f32: out = 1 - bit(dilate(~d1)).
// ---------------------------------------------------------------------------
__global__ void erode_unpack_kernel(const u64* __restrict__ in, float* __restrict__ out) {
  __shared__ u64 hm[68][16];
  __shared__ u64 d2[64][16];
  int bx = blockIdx.x & 3;
  int by = blockIdx.x >> 2;
  int r0 = by * 64, c0 = bx * 16;
  int tid = threadIdx.x;
  for (int it = tid; it < 68 * 16; it += 256) {
    int rr = it >> 4;
    int cc = it & 15;
    int gy = r0 - 2 + rr;
    int gx = c0 + cc;
    u64 m = 0, l = 0, r = 0;
    if ((unsigned)gy < (unsigned)HH) {
      m = ~in[gy * WPR + gx];
      l = (gx > 0) ? ~in[gy * WPR + gx - 1] : 0ull;
      r = (gx < WPR - 1) ? ~in[gy * WPR + gx + 1] : 0ull;
    }
    hm[rr][cc] = m | (m << 1) | (m << 2) | (m >> 1) | (m >> 2)
                   | (l >> 62) | (l >> 63) | (r << 62) | (r << 63);
  }
  __syncthreads();
  for (int it = tid; it < 64 * 16; it += 256) {
    int rr = it >> 4;
    int cc = it & 15;
    d2[rr][cc] = hm[rr][cc] | hm[rr + 1][cc] | hm[rr + 2][cc] | hm[rr + 3][cc] | hm[rr + 4][cc];
  }
  __syncthreads();
  int colbase = c0 * 64;
  for (int it = tid; it < 64 * 256; it += 256) {
    int rr = it >> 8;
    int px0 = (it & 255) * 4;
    u64 w = d2[rr][px0 >> 6];
    int sh = px0 & 63;
    float4 o;
    o.x = (float)(1 - (int)((w >> (sh + 0)) & 1ull));
    o.y = (float)(1 - (int)((w >> (sh + 1)) & 1ull));
    o.z = (float)(1 - (int)((w >> (sh + 2)) & 1ull));
    o.w = (float)(1 - (int)((w >> (sh + 3)) & 1ull));
    *(float4*)(out + (size_t)(r0 + rr) * WW + colbase + px0) = o;
  }
}

// ---------------------------------------------------------------------------
extern "C" void kernel_launch(void* const* d_in, const int* in_sizes, int n_in,
                              void* d_out, int out_size, void* d_ws, size_t ws_size,
                              hipStream_t stream) {
  const float* x = (const float*)d_in[0];
  if (n_in > 1 && in_sizes[0] != NPIX) x = (const float*)d_in[1];
  float* out = (float*)d_out;
  char* ws = (char*)d_ws;

  // workspace layout — TOTAL ~7.4 MB
  // hist and bandcnt are adjacent so one memset clears both.
  const size_t OFF_HIST = 0;          // 2,097,152
  const size_t OFF_BCNT = 2097152;    // 256
  const size_t OFF_TH   = 2097408;    // 256
  const size_t OFF_PKA  = 2097664;    // 2,097,152
  const size_t OFF_PKB  = 4194816;    // 2,097,152
  const size_t OFF_BINS = 6291968;    // 1,024
  const size_t OFF_VHL  = 6292992;    // 512
  const size_t OFF_BAND = 6293504;    // 1,048,576 (end ~7.34 MB)
  uint32_t* hist    = (uint32_t*)(ws + OFF_HIST);
  uint32_t* bandcnt = (uint32_t*)(ws + OFF_BCNT);
  float*    th      = (float*)(ws + OFF_TH);
  u64*      PKA     = (u64*)(ws + OFF_PKA);
  u64*      PKB     = (u64*)(ws + OFF_PKB);
  int4*     bins4   = (int4*)(ws + OFF_BINS);
  float2*   vhl     = (float2*)(ws + OFF_VHL);
  float*    band    = (float*)(ws + OFF_BAND);

  float* blurred = out;   // blur lives in d_out; erode_unpack rewrites it

  const int TPB = 256;
  const int NB32 = NPIX / 32 / TPB;   // 2048 blocks (32 px/thread kernels)

  // one memset covers hist (2 MB) + bandcnt (256 B), adjacent in ws
  hipMemsetAsync(hist, 0, (size_t)NFRAG * NBINS * sizeof(uint32_t) + NFRAG * sizeof(uint32_t), stream);
  blur_hist_kernel<<<1024, 512, 0, stream>>>(x, blurred, hist);
  findcrit_kernel<<<NFRAG, TPB, 0, stream>>>(hist, bins4);
  gather_kernel<<<NB32, TPB, 0, stream>>>(blurred, bins4, band, bandcnt);
  select_kernel<<<NFRAG, TPB, 0, stream>>>(band, bandcnt, bins4, vhl);
  walk_kernel<<<1, 64, 0, stream>>>(vhl, th);
  mask_pack_kernel<<<NB32, TPB, 0, stream>>>(blurred, th, PKA);
  dilate_kernel<<<256, TPB, 0, stream>>>(PKA, PKB);
  erode_unpack_kernel<<<256, TPB, 0, stream>>>(PKB, out);
}

// Round 4
// 331.383 us; speedup vs baseline: 1.0203x; 1.0203x over previous
//
#include <hip/hip_runtime.h>
#include <stdint.h>

#define HH 4096
#define WW 4096
#define NPIX (HH * WW)
#define NBINS 8192
#define NFRAG 64
#define FRAG_PIX (512 * 512)   // 2^18
#define WPR 64                 // u64 words per row (4096/64)
#define NWORDS (HH * WPR)      // 262144
#define CAP 4096               // per-fragment critical-band capacity

// Reference stop conditions (integer-exact):
//   phase0 stop: cnt >= 31458 <=> th < V_HI,  V_HI = v_sorted[230686]
//   phase1 stop: cnt <= 20971 <=> th >= V_LO, V_LO = v_sorted[241172]
#define RANK_HI 230686u
#define RANK_LO 241172u

typedef unsigned long long u64;

__device__ __forceinline__ int frag_of(int py, int px) {
  return ((py >> 9) << 3) + (px >> 9);
}

__device__ __forceinline__ int bin_of(float v) {
  int b = (int)(v * 8192.0f);   // monotone f32 map
  if (b < 0) b = 0;
  if (b > NBINS - 1) b = NBINS - 1;
  return b;
}

// spread 16 bits so bit i lands at position 4i
__device__ __forceinline__ u64 spread4(u64 x) {
  x &= 0xFFFFull;
  x = (x | (x << 24)) & 0x000000FF000000FFull;
  x = (x | (x << 12)) & 0x000F000F000F000Full;
  x = (x | (x << 6))  & 0x0303030303030303ull;
  x = (x | (x << 3))  & 0x1111111111111111ull;
  return x;
}

// ---------------------------------------------------------------------------
// VERIFIED bit-exact blur tree (numpy pairwise_sum n=25 over materialized
// (windows*k), row-major taps, OOB -> exact 0). DO NOT TOUCH.
// ---------------------------------------------------------------------------
__device__ __forceinline__ float blur_tree(const float rowbuf[5][8], int e) {
  const float K = (float)(1.0 / 25.0);
  float p[25];
#pragma unroll
  for (int i = 0; i < 25; ++i) {
    p[i] = __fmul_rn(rowbuf[i / 5][e + (i % 5)], K);
  }
  float r0 = __fadd_rn(__fadd_rn(p[0], p[8]),  p[16]);
  float r1 = __fadd_rn(__fadd_rn(p[1], p[9]),  p[17]);
  float r2 = __fadd_rn(__fadd_rn(p[2], p[10]), p[18]);
  float r3 = __fadd_rn(__fadd_rn(p[3], p[11]), p[19]);
  float r4 = __fadd_rn(__fadd_rn(p[4], p[12]), p[20]);
  float r5 = __fadd_rn(__fadd_rn(p[5], p[13]), p[21]);
  float r6 = __fadd_rn(__fadd_rn(p[6], p[14]), p[22]);
  float r7 = __fadd_rn(__fadd_rn(p[7], p[15]), p[23]);
  float res = __fadd_rn(
      __fadd_rn(__fadd_rn(r0, r1), __fadd_rn(r2, r3)),
      __fadd_rn(__fadd_rn(r4, r5), __fadd_rn(r6, r7)));
  return __fadd_rn(res, p[24]);
}

// ---------------------------------------------------------------------------
// 1) FUSED blur + per-fragment LDS histogram.
//    4x4 output patch per thread: 8 rows x 8 cols of input in registers,
//    24 vector loads -> 16 outputs, 4 blur trees of ILP between stalls.
// ---------------------------------------------------------------------------
__global__ void __launch_bounds__(512)
blur_hist_kernel(const float* __restrict__ x,
                 float* __restrict__ out,
                 uint32_t* __restrict__ hist) {
  __shared__ uint32_t lh[NBINS];
  int tid = threadIdx.x;
  for (int i = tid; i < NBINS; i += 512) lh[i] = 0;
  __syncthreads();
  int f = blockIdx.x >> 4;
  int s = blockIdx.x & 15;
  int row0 = (f >> 3) * 512 + s * 32;
  int col0 = (f & 7) * 512;
  // 8 patch-rows x 128 patch-cols per 32x512 slice; 512 threads -> 2 iters
  for (int it = tid; it < 8 * 128; it += 512) {
    int pr = it >> 7;          // patch row 0..7
    int c4 = it & 127;         // patch col 0..127
    int py = row0 + pr * 4;
    int px = col0 + c4 * 4;
    float rb[8][8];
    bool interior = (px >= 2) && (px + 5 < WW);
#pragma unroll
    for (int r = 0; r < 8; ++r) {
      int yy = py - 2 + r;
      if ((unsigned)yy >= (unsigned)HH) {
#pragma unroll
        for (int j = 0; j < 8; ++j) rb[r][j] = 0.0f;
      } else if (interior) {
        const float* rp = x + (size_t)yy * WW + px;
        float2 L = *(const float2*)(rp - 2);
        float4 M = *(const float4*)(rp);
        float2 R = *(const float2*)(rp + 4);
        rb[r][0] = L.x; rb[r][1] = L.y;
        rb[r][2] = M.x; rb[r][3] = M.y;
        rb[r][4] = M.z; rb[r][5] = M.w;
        rb[r][6] = R.x; rb[r][7] = R.y;
      } else {
#pragma unroll
        for (int j = 0; j < 8; ++j) {
          int xx = px - 2 + j;
          rb[r][j] = ((unsigned)xx < (unsigned)WW) ? x[(size_t)yy * WW + xx] : 0.0f;
        }
      }
    }
#pragma unroll
    for (int orow = 0; orow < 4; ++orow) {
      float4 res;
      res.x = blur_tree(rb + orow, 0);
      res.y = blur_tree(rb + orow, 1);
      res.z = blur_tree(rb + orow, 2);
      res.w = blur_tree(rb + orow, 3);
      *(float4*)(out + (size_t)(py + orow) * WW + px) = res;
      atomicAdd(&lh[bin_of(res.x)], 1u);
      atomicAdd(&lh[bin_of(res.y)], 1u);
      atomicAdd(&lh[bin_of(res.z)], 1u);
      atomicAdd(&lh[bin_of(res.w)], 1u);
    }
  }
  __syncthreads();
  uint32_t* hf = hist + f * NBINS;
  for (int i = tid; i < NBINS; i += 512) {
    uint32_t c = lh[i];
    if (c) atomicAdd(&hf[i], c);
  }
}

// ---------------------------------------------------------------------------
// 2) find critical buckets + local ranks. bins4[f] = (bhi, blo, khi, klo).
// ---------------------------------------------------------------------------
__global__ void findcrit_kernel(const uint32_t* __restrict__ hist,
                                int4* __restrict__ bins4) {
  __shared__ uint32_t segsum[256];
  __shared__ uint32_t segoff[256];
  __shared__ int4 result;
  int f = blockIdx.x;
  int tid = threadIdx.x;
  const uint32_t* hf = hist + f * NBINS;
  int base = tid * 32;
  uint32_t h32[32];
  uint32_t s = 0;
  for (int i = 0; i < 32; ++i) { h32[i] = hf[base + i]; s += h32[i]; }
  segsum[tid] = s;
  __syncthreads();
  if (tid == 0) {
    uint32_t a = 0;
    for (int i = 0; i < 256; ++i) { segoff[i] = a; a += segsum[i]; }
  }
  __syncthreads();
  uint32_t st = segoff[tid];
  uint32_t en = st + segsum[tid];
  if (st <= RANK_HI && RANK_HI < en) {
    uint32_t a = st;
    for (int i = 0; i < 32; ++i) {
      uint32_t nx = a + h32[i];
      if (RANK_HI < nx) { result.x = base + i; result.z = (int)(RANK_HI - a); break; }
      a = nx;
    }
  }
  if (st <= RANK_LO && RANK_LO < en) {
    uint32_t a = st;
    for (int i = 0; i < 32; ++i) {
      uint32_t nx = a + h32[i];
      if (RANK_LO < nx) { result.y = base + i; result.w = (int)(RANK_LO - a); break; }
      a = nx;
    }
  }
  __syncthreads();
  if (tid == 0) bins4[f] = result;
}

// ---------------------------------------------------------------------------
// 3) gather critical-bucket values — 32 px/thread staged through LDS via
//    global_load_lds: each wave ISSUES all 8 16B-per-lane loads before one
//    vmcnt(0), so 8 transactions are in flight by construction (the R2/R3
//    compiler kept sinking register loads -> serial latency). LDS regions
//    are wave-private: no barrier, just vmcnt.
// ---------------------------------------------------------------------------
__global__ void __launch_bounds__(256)
gather_kernel(const float* __restrict__ blur,
              const int4* __restrict__ bins4,
              float* __restrict__ band,
              uint32_t* __restrict__ bandcnt) {
  __shared__ float stage[8192];   // 32 KB: [4 waves][8 k][64 lanes x 4 floats]
  const int T = NPIX / 32;        // 524,288 threads, 8 float4-slices each
  int tid = threadIdx.x;
  int wave = tid >> 6, lane = tid & 63;
  int t = blockIdx.x * 256 + tid;
  float* wbase = stage + wave * 2048;   // wave-uniform LDS base
#pragma unroll
  for (int k = 0; k < 8; ++k) {
    const float* gp = blur + (size_t)(t + k * T) * 4;
    __builtin_amdgcn_global_load_lds(
        (const __attribute__((address_space(1))) void*)gp,
        (__attribute__((address_space(3))) void*)(wbase + k * 256),
        16, 0, 0);
  }
  asm volatile("s_waitcnt vmcnt(0)" ::: "memory");
#pragma unroll
  for (int k = 0; k < 8; ++k) {
    float4 v = *(const float4*)(wbase + k * 256 + lane * 4);
    int p0 = (t + k * T) * 4;
    int f = frag_of(p0 >> 12, p0 & (WW - 1));
    int4 info = bins4[f];
    float vv[4] = {v.x, v.y, v.z, v.w};
#pragma unroll
    for (int e = 0; e < 4; ++e) {
      int b = bin_of(vv[e]);
      if (b == info.x || b == info.y) {
        uint32_t pos = atomicAdd(&bandcnt[f], 1u);
        if (pos < CAP) band[(size_t)f * CAP + pos] = vv[e];
      }
    }
  }
}

// ---------------------------------------------------------------------------
// 4) exact order-statistic selection within the critical buckets
// ---------------------------------------------------------------------------
__global__ void select_kernel(const float* __restrict__ band,
                              const uint32_t* __restrict__ bandcnt,
                              const int4* __restrict__ bins4,
                              float2* __restrict__ vhl) {
  __shared__ float wv[CAP];
  __shared__ float res[2];
  int f = blockIdx.x;
  int tid = threadIdx.x;
  int n = (int)bandcnt[f];
  if (n > CAP) n = CAP;
  for (int i = tid; i < n; i += 256) wv[i] = band[(size_t)f * CAP + i];
  __syncthreads();
  int4 info = bins4[f];
#pragma unroll
  for (int sel = 0; sel < 2; ++sel) {
    int tb = sel ? info.y : info.x;
    int k  = sel ? info.w : info.z;
    for (int i = tid; i < n; i += 256) {
      float w = wv[i];
      if (bin_of(w) != tb) continue;
      int less = 0, leq = 0;
      for (int j = 0; j < n; ++j) {
        float u = wv[j];
        if (bin_of(u) == tb) {
          less += (u < w) ? 1 : 0;
          leq  += (u <= w) ? 1 : 0;
        }
      }
      if (less <= k && k < leq) res[sel] = w;   // unique value; benign race
    }
  }
  __syncthreads();
  if (tid == 0) vhl[f] = make_float2(res[0], res[1]);
}

// ---------------------------------------------------------------------------
// 5) threshold walk — branchless predicated steps (16 per exit check).
//    Each conditional step is EXACTLY the reference's while-iteration:
//    taken  -> th = __fadd_rn(th, ±step) ; not-taken -> no-op.
// ---------------------------------------------------------------------------
__global__ void walk_kernel(const float2* __restrict__ vhl, float* __restrict__ th_out) {
  int lane = threadIdx.x;
  float2 mine = vhl[lane];   // lane f holds fragment f's (V_HI, V_LO)
  float th = 0.5f;           // TH1_INIT
  for (int f = 0; f < NFRAG; ++f) {
    float VH = __shfl(mine.x, f);
    float VL = __shfl(mine.y, f);
    // phase 0: while th >= VH: th -= 0.0005
    while (th >= VH) {
#pragma unroll
      for (int i = 0; i < 16; ++i) {
        float t2 = __fadd_rn(th, -0.0005f);
        th = (th >= VH) ? t2 : th;
      }
    }
    // phase 1: while th < VL: th += 0.0005
    while (th < VL) {
#pragma unroll
      for (int i = 0; i < 16; ++i) {
        float t2 = __fadd_rn(th, 0.0005f);
        th = (th < VL) ? t2 : th;
      }
    }
    if (lane == 0) th_out[f] = th;
  }
}

// ---------------------------------------------------------------------------
// 6) mask + bit-pack — 32 px/thread via the same global_load_lds staging,
//    ballot interleave. Word mapping unchanged: wave-base group (g - lane)
//    stays 64-aligned, T multiple of 16 -> exact same output bits.
// ---------------------------------------------------------------------------
__global__ void __launch_bounds__(256)
mask_pack_kernel(const float* __restrict__ blur,
                 const float* __restrict__ th,
                 u64* __restrict__ pk) {
  __shared__ float stage[8192];   // 32 KB wave-private staging
  const int T = NPIX / 32;        // 524,288 threads, 8 groups each
  int tid = threadIdx.x;
  int wave = tid >> 6, lane = tid & 63;
  int t = blockIdx.x * 256 + tid;
  float* wbase = stage + wave * 2048;
#pragma unroll
  for (int k = 0; k < 8; ++k) {
    const float* gp = blur + (size_t)(t + k * T) * 4;
    __builtin_amdgcn_global_load_lds(
        (const __attribute__((address_space(1))) void*)gp,
        (__attribute__((address_space(3))) void*)(wbase + k * 256),
        16, 0, 0);
  }
  asm volatile("s_waitcnt vmcnt(0)" ::: "memory");
#pragma unroll
  for (int k = 0; k < 8; ++k) {
    float4 v = *(const float4*)(wbase + k * 256 + lane * 4);
    int g = t + k * T;           // 4-px group index
    int p0 = g * 4;
    float tf = th[frag_of(p0 >> 12, p0 & (WW - 1))];
    u64 b0 = __ballot(v.x > tf);
    u64 b1 = __ballot(v.y > tf);
    u64 b2 = __ballot(v.z > tf);
    u64 b3 = __ballot(v.w > tf);
    if ((lane & 15) == 0) {
      int sh = lane;             // 0,16,32,48
      u64 w = spread4(b0 >> sh) | (spread4(b1 >> sh) << 1)
            | (spread4(b2 >> sh) << 2) | (spread4(b3 >> sh) << 3);
      int base_word = ((g - lane) * 4) >> 6;
      pk[base_word + (lane >> 4)] = w;
    }
  }
}

// ---------------------------------------------------------------------------
// 7) fused dilate (H+V) on packed bits; OOB = 0 (clipped window).
// ---------------------------------------------------------------------------
__global__ void dilate_kernel(const u64* __restrict__ in, u64* __restrict__ out) {
  __shared__ u64 hm[68][16];
  int bx = blockIdx.x & 3;
  int by = blockIdx.x >> 2;
  int r0 = by * 64, c0 = bx * 16;
  int tid = threadIdx.x;
  for (int it = tid; it < 68 * 16; it += 256) {
    int rr = it >> 4;
    int cc = it & 15;
    int gy = r0 - 2 + rr;
    int gx = c0 + cc;
    u64 m = 0, l = 0, r = 0;
    if ((unsigned)gy < (unsigned)HH) {
      m = in[gy * WPR + gx];
      l = (gx > 0) ? in[gy * WPR + gx - 1] : 0ull;
      r = (gx < WPR - 1) ? in[gy * WPR + gx + 1] : 0ull;
    }
    hm[rr][cc] = m | (m << 1) | (m << 2) | (m >> 1) | (m >> 2)
                   | (l >> 62) | (l >> 63) | (r << 62) | (r << 63);
  }
  __syncthreads();
  for (int it = tid; it < 64 * 16; it += 256) {
    int rr = it >> 4;
    int cc = it & 15;
    u64 v = hm[rr][cc] | hm[rr + 1][cc] | hm[rr + 2][cc] | hm[rr + 3][cc] | hm[rr + 4][cc];
    out[(r0 + rr) * WPR + c0 + cc] = v;
  }
}

// ---------------------------------------------------------------------------
// 8) fused erode (De Morgan) + unpack to f32: out = 1 - bit(dilate(~d1)).
// ---------------------------------------------------------------------------
__global__ void erode_unpack_kernel(const u64* __restrict__ in, float* __restrict__ out) {
  __shared__ u64 hm[68][16];
  __shared__ u64 d2[64][16];
  int bx = blockIdx.x & 3;
  int by = blockIdx.x >> 2;
  int r0 = by * 64, c0 = bx * 16;
  int tid = threadIdx.x;
  for (int it = tid; it < 68 * 16; it += 256) {
    int rr = it >> 4;
    int cc = it & 15;
    int gy = r0 - 2 + rr;
    int gx = c0 + cc;
    u64 m = 0, l = 0, r = 0;
    if ((unsigned)gy < (unsigned)HH) {
      m = ~in[gy * WPR + gx];
      l = (gx > 0) ? ~in[gy * WPR + gx - 1] : 0ull;
      r = (gx < WPR - 1) ? ~in[gy * WPR + gx + 1] : 0ull;
    }
    hm[rr][cc] = m | (m << 1) | (m << 2) | (m >> 1) | (m >> 2)
                   | (l >> 62) | (l >> 63) | (r << 62) | (r << 63);
  }
  __syncthreads();
  for (int it = tid; it < 64 * 16; it += 256) {
    int rr = it >> 4;
    int cc = it & 15;
    d2[rr][cc] = hm[rr][cc] | hm[rr + 1][cc] | hm[rr + 2][cc] | hm[rr + 3][cc] | hm[rr + 4][cc];
  }
  __syncthreads();
  int colbase = c0 * 64;
  for (int it = tid; it < 64 * 256; it += 256) {
    int rr = it >> 8;
    int px0 = (it & 255) * 4;
    u64 w = d2[rr][px0 >> 6];
    int sh = px0 & 63;
    float4 o;
    o.x = (float)(1 - (int)((w >> (sh + 0)) & 1ull));
    o.y = (float)(1 - (int)((w >> (sh + 1)) & 1ull));
    o.z = (float)(1 - (int)((w >> (sh + 2)) & 1ull));
    o.w = (float)(1 - (int)((w >> (sh + 3)) & 1ull));
    *(float4*)(out + (size_t)(r0 + rr) * WW + colbase + px0) = o;
  }
}

// ---------------------------------------------------------------------------
extern "C" void kernel_launch(void* const* d_in, const int* in_sizes, int n_in,
                              void* d_out, int out_size, void* d_ws, size_t ws_size,
                              hipStream_t stream) {
  const float* x = (const float*)d_in[0];
  if (n_in > 1 && in_sizes[0] != NPIX) x = (const float*)d_in[1];
  float* out = (float*)d_out;
  char* ws = (char*)d_ws;

  // workspace layout — TOTAL ~7.4 MB
  // hist and bandcnt are adjacent so one memset clears both.
  const size_t OFF_HIST = 0;          // 2,097,152
  const size_t OFF_BCNT = 2097152;    // 256
  const size_t OFF_TH   = 2097408;    // 256
  const size_t OFF_PKA  = 2097664;    // 2,097,152
  const size_t OFF_PKB  = 4194816;    // 2,097,152
  const size_t OFF_BINS = 6291968;    // 1,024
  const size_t OFF_VHL  = 6292992;    // 512
  const size_t OFF_BAND = 6293504;    // 1,048,576 (end ~7.34 MB)
  uint32_t* hist    = (uint32_t*)(ws + OFF_HIST);
  uint32_t* bandcnt = (uint32_t*)(ws + OFF_BCNT);
  float*    th      = (float*)(ws + OFF_TH);
  u64*      PKA     = (u64*)(ws + OFF_PKA);
  u64*      PKB     = (u64*)(ws + OFF_PKB);
  int4*     bins4   = (int4*)(ws + OFF_BINS);
  float2*   vhl     = (float2*)(ws + OFF_VHL);
  float*    band    = (float*)(ws + OFF_BAND);

  float* blurred = out;   // blur lives in d_out; erode_unpack rewrites it

  const int TPB = 256;
  const int NB32 = NPIX / 32 / TPB;   // 2048 blocks (32 px/thread kernels)

  // one memset covers hist (2 MB) + bandcnt (256 B), adjacent in ws
  hipMemsetAsync(hist, 0, (size_t)NFRAG * NBINS * sizeof(uint32_t) + NFRAG * sizeof(uint32_t), stream);
  blur_hist_kernel<<<1024, 512, 0, stream>>>(x, blurred, hist);
  findcrit_kernel<<<NFRAG, TPB, 0, stream>>>(hist, bins4);
  gather_kernel<<<NB32, TPB, 0, stream>>>(blurred, bins4, band, bandcnt);
  select_kernel<<<NFRAG, TPB, 0, stream>>>(band, bandcnt, bins4, vhl);
  walk_kernel<<<1, 64, 0, stream>>>(vhl, th);
  mask_pack_kernel<<<NB32, TPB, 0, stream>>>(blurred, th, PKA);
  dilate_kernel<<<256, TPB, 0, stream>>>(PKA, PKB);
  erode_unpack_kernel<<<256, TPB, 0, stream>>>(PKB, out);
}

// Round 5
// 315.362 us; speedup vs baseline: 1.0721x; 1.0508x over previous
//
#include <hip/hip_runtime.h>
#include <stdint.h>

#define HH 4096
#define WW 4096
#define NPIX (HH * WW)
#define NBINS 8192
#define NFRAG 64
#define FRAG_PIX (512 * 512)   // 2^18
#define WPR 64                 // u64 words per row (4096/64)
#define NWORDS (HH * WPR)      // 262144
#define CAP 4096               // per-fragment critical-band capacity

// Reference stop conditions (integer-exact):
//   phase0 stop: cnt >= 31458 <=> th < V_HI,  V_HI = v_sorted[230686]
//   phase1 stop: cnt <= 20971 <=> th >= V_LO, V_LO = v_sorted[241172]
#define RANK_HI 230686u
#define RANK_LO 241172u

typedef unsigned long long u64;

__device__ __forceinline__ int frag_of(int py, int px) {
  return ((py >> 9) << 3) + (px >> 9);
}

__device__ __forceinline__ int bin_of(float v) {
  int b = (int)(v * 8192.0f);   // monotone f32 map
  if (b < 0) b = 0;
  if (b > NBINS - 1) b = NBINS - 1;
  return b;
}

// spread 16 bits so bit i lands at position 4i
__device__ __forceinline__ u64 spread4(u64 x) {
  x &= 0xFFFFull;
  x = (x | (x << 24)) & 0x000000FF000000FFull;
  x = (x | (x << 12)) & 0x000F000F000F000Full;
  x = (x | (x << 6))  & 0x0303030303030303ull;
  x = (x | (x << 3))  & 0x1111111111111111ull;
  return x;
}

// ---------------------------------------------------------------------------
// VERIFIED bit-exact blur tree (numpy pairwise_sum n=25 over materialized
// (windows*k), row-major taps, OOB -> exact 0). DO NOT TOUCH.
// ---------------------------------------------------------------------------
__device__ __forceinline__ float blur_tree(const float rowbuf[5][8], int e) {
  const float K = (float)(1.0 / 25.0);
  float p[25];
#pragma unroll
  for (int i = 0; i < 25; ++i) {
    p[i] = __fmul_rn(rowbuf[i / 5][e + (i % 5)], K);
  }
  float r0 = __fadd_rn(__fadd_rn(p[0], p[8]),  p[16]);
  float r1 = __fadd_rn(__fadd_rn(p[1], p[9]),  p[17]);
  float r2 = __fadd_rn(__fadd_rn(p[2], p[10]), p[18]);
  float r3 = __fadd_rn(__fadd_rn(p[3], p[11]), p[19]);
  float r4 = __fadd_rn(__fadd_rn(p[4], p[12]), p[20]);
  float r5 = __fadd_rn(__fadd_rn(p[5], p[13]), p[21]);
  float r6 = __fadd_rn(__fadd_rn(p[6], p[14]), p[22]);
  float r7 = __fadd_rn(__fadd_rn(p[7], p[15]), p[23]);
  float res = __fadd_rn(
      __fadd_rn(__fadd_rn(r0, r1), __fadd_rn(r2, r3)),
      __fadd_rn(__fadd_rn(r4, r5), __fadd_rn(r6, r7)));
  return __fadd_rn(res, p[24]);
}

// ---------------------------------------------------------------------------
// 1) FUSED blur + per-fragment LDS histogram.
//    4x4 output patch per thread: 8 rows x 8 cols of input in registers,
//    24 vector loads -> 16 outputs, 4 blur trees of ILP between stalls.
// ---------------------------------------------------------------------------
__global__ void __launch_bounds__(512)
blur_hist_kernel(const float* __restrict__ x,
                 float* __restrict__ out,
                 uint32_t* __restrict__ hist) {
  __shared__ uint32_t lh[NBINS];
  int tid = threadIdx.x;
  for (int i = tid; i < NBINS; i += 512) lh[i] = 0;
  __syncthreads();
  int f = blockIdx.x >> 4;
  int s = blockIdx.x & 15;
  int row0 = (f >> 3) * 512 + s * 32;
  int col0 = (f & 7) * 512;
  // 8 patch-rows x 128 patch-cols per 32x512 slice; 512 threads -> 2 iters
  for (int it = tid; it < 8 * 128; it += 512) {
    int pr = it >> 7;          // patch row 0..7
    int c4 = it & 127;         // patch col 0..127
    int py = row0 + pr * 4;
    int px = col0 + c4 * 4;
    float rb[8][8];
    bool interior = (px >= 2) && (px + 5 < WW);
#pragma unroll
    for (int r = 0; r < 8; ++r) {
      int yy = py - 2 + r;
      if ((unsigned)yy >= (unsigned)HH) {
#pragma unroll
        for (int j = 0; j < 8; ++j) rb[r][j] = 0.0f;
      } else if (interior) {
        const float* rp = x + (size_t)yy * WW + px;
        float2 L = *(const float2*)(rp - 2);
        float4 M = *(const float4*)(rp);
        float2 R = *(const float2*)(rp + 4);
        rb[r][0] = L.x; rb[r][1] = L.y;
        rb[r][2] = M.x; rb[r][3] = M.y;
        rb[r][4] = M.z; rb[r][5] = M.w;
        rb[r][6] = R.x; rb[r][7] = R.y;
      } else {
#pragma unroll
        for (int j = 0; j < 8; ++j) {
          int xx = px - 2 + j;
          rb[r][j] = ((unsigned)xx < (unsigned)WW) ? x[(size_t)yy * WW + xx] : 0.0f;
        }
      }
    }
#pragma unroll
    for (int orow = 0; orow < 4; ++orow) {
      float4 res;
      res.x = blur_tree(rb + orow, 0);
      res.y = blur_tree(rb + orow, 1);
      res.z = blur_tree(rb + orow, 2);
      res.w = blur_tree(rb + orow, 3);
      *(float4*)(out + (size_t)(py + orow) * WW + px) = res;
      atomicAdd(&lh[bin_of(res.x)], 1u);
      atomicAdd(&lh[bin_of(res.y)], 1u);
      atomicAdd(&lh[bin_of(res.z)], 1u);
      atomicAdd(&lh[bin_of(res.w)], 1u);
    }
  }
  __syncthreads();
  uint32_t* hf = hist + f * NBINS;
  for (int i = tid; i < NBINS; i += 512) {
    uint32_t c = lh[i];
    if (c) atomicAdd(&hf[i], c);
  }
}

// ---------------------------------------------------------------------------
// 2) find critical buckets + local ranks. bins4[f] = (bhi, blo, khi, klo).
// ---------------------------------------------------------------------------
__global__ void findcrit_kernel(const uint32_t* __restrict__ hist,
                                int4* __restrict__ bins4) {
  __shared__ uint32_t segsum[256];
  __shared__ uint32_t segoff[256];
  __shared__ int4 result;
  int f = blockIdx.x;
  int tid = threadIdx.x;
  const uint32_t* hf = hist + f * NBINS;
  int base = tid * 32;
  uint32_t h32[32];
  uint32_t s = 0;
  for (int i = 0; i < 32; ++i) { h32[i] = hf[base + i]; s += h32[i]; }
  segsum[tid] = s;
  __syncthreads();
  if (tid == 0) {
    uint32_t a = 0;
    for (int i = 0; i < 256; ++i) { segoff[i] = a; a += segsum[i]; }
  }
  __syncthreads();
  uint32_t st = segoff[tid];
  uint32_t en = st + segsum[tid];
  if (st <= RANK_HI && RANK_HI < en) {
    uint32_t a = st;
    for (int i = 0; i < 32; ++i) {
      uint32_t nx = a + h32[i];
      if (RANK_HI < nx) { result.x = base + i; result.z = (int)(RANK_HI - a); break; }
      a = nx;
    }
  }
  if (st <= RANK_LO && RANK_LO < en) {
    uint32_t a = st;
    for (int i = 0; i < 32; ++i) {
      uint32_t nx = a + h32[i];
      if (RANK_LO < nx) { result.y = base + i; result.w = (int)(RANK_LO - a); break; }
      a = nx;
    }
  }
  __syncthreads();
  if (tid == 0) bins4[f] = result;
}

// ---------------------------------------------------------------------------
// 3) gather critical-bucket values — 16 px/thread, 4 float4 loads.
//    blur now lives in d_ws (normal cached memory); with cached reads this
//    is BW-bound regardless of load scheduling.
// ---------------------------------------------------------------------------
__global__ void __launch_bounds__(256)
gather_kernel(const float* __restrict__ blur,
              const int4* __restrict__ bins4,
              float* __restrict__ band,
              uint32_t* __restrict__ bandcnt) {
  const int T = NPIX / 16;   // 1,048,576 threads
  int t = blockIdx.x * blockDim.x + threadIdx.x;
  float4 v[4];
#pragma unroll
  for (int k = 0; k < 4; ++k) {
    v[k] = *(const float4*)(blur + (size_t)(t + k * T) * 4);
  }
#pragma unroll
  for (int k = 0; k < 4; ++k) {
    int p0 = (t + k * T) * 4;
    int f = frag_of(p0 >> 12, p0 & (WW - 1));
    int4 info = bins4[f];
    float vv[4] = {v[k].x, v[k].y, v[k].z, v[k].w};
#pragma unroll
    for (int e = 0; e < 4; ++e) {
      int b = bin_of(vv[e]);
      if (b == info.x || b == info.y) {
        uint32_t pos = atomicAdd(&bandcnt[f], 1u);
        if (pos < CAP) band[(size_t)f * CAP + pos] = vv[e];
      }
    }
  }
}

// ---------------------------------------------------------------------------
// 4) exact order-statistic selection within the critical buckets
// ---------------------------------------------------------------------------
__global__ void select_kernel(const float* __restrict__ band,
                              const uint32_t* __restrict__ bandcnt,
                              const int4* __restrict__ bins4,
                              float2* __restrict__ vhl) {
  __shared__ float wv[CAP];
  __shared__ float res[2];
  int f = blockIdx.x;
  int tid = threadIdx.x;
  int n = (int)bandcnt[f];
  if (n > CAP) n = CAP;
  for (int i = tid; i < n; i += 256) wv[i] = band[(size_t)f * CAP + i];
  __syncthreads();
  int4 info = bins4[f];
#pragma unroll
  for (int sel = 0; sel < 2; ++sel) {
    int tb = sel ? info.y : info.x;
    int k  = sel ? info.w : info.z;
    for (int i = tid; i < n; i += 256) {
      float w = wv[i];
      if (bin_of(w) != tb) continue;
      int less = 0, leq = 0;
      for (int j = 0; j < n; ++j) {
        float u = wv[j];
        if (bin_of(u) == tb) {
          less += (u < w) ? 1 : 0;
          leq  += (u <= w) ? 1 : 0;
        }
      }
      if (less <= k && k < leq) res[sel] = w;   // unique value; benign race
    }
  }
  __syncthreads();
  if (tid == 0) vhl[f] = make_float2(res[0], res[1]);
}

// ---------------------------------------------------------------------------
// 5) threshold walk — branchless predicated steps (16 per exit check).
//    Each conditional step is EXACTLY the reference's while-iteration:
//    taken  -> th = __fadd_rn(th, ±step) ; not-taken -> no-op.
// ---------------------------------------------------------------------------
__global__ void walk_kernel(const float2* __restrict__ vhl, float* __restrict__ th_out) {
  int lane = threadIdx.x;
  float2 mine = vhl[lane];   // lane f holds fragment f's (V_HI, V_LO)
  float th = 0.5f;           // TH1_INIT
  for (int f = 0; f < NFRAG; ++f) {
    float VH = __shfl(mine.x, f);
    float VL = __shfl(mine.y, f);
    // phase 0: while th >= VH: th -= 0.0005
    while (th >= VH) {
#pragma unroll
      for (int i = 0; i < 16; ++i) {
        float t2 = __fadd_rn(th, -0.0005f);
        th = (th >= VH) ? t2 : th;
      }
    }
    // phase 1: while th < VL: th += 0.0005
    while (th < VL) {
#pragma unroll
      for (int i = 0; i < 16; ++i) {
        float t2 = __fadd_rn(th, 0.0005f);
        th = (th < VL) ? t2 : th;
      }
    }
    if (lane == 0) th_out[f] = th;
  }
}

// ---------------------------------------------------------------------------
// 6) mask + bit-pack — 16 px/thread, 4 float4 loads, ballot interleave.
// ---------------------------------------------------------------------------
__global__ void __launch_bounds__(256)
mask_pack_kernel(const float* __restrict__ blur,
                 const float* __restrict__ th,
                 u64* __restrict__ pk) {
  const int T = NPIX / 16;   // 1,048,576 threads
  int t = blockIdx.x * blockDim.x + threadIdx.x;
  float4 v[4];
#pragma unroll
  for (int k = 0; k < 4; ++k) {
    v[k] = *(const float4*)(blur + (size_t)(t + k * T) * 4);
  }
  int lane = threadIdx.x & 63;
#pragma unroll
  for (int k = 0; k < 4; ++k) {
    int g = t + k * T;           // 4-px group index
    int p0 = g * 4;
    float tf = th[frag_of(p0 >> 12, p0 & (WW - 1))];
    u64 b0 = __ballot(v[k].x > tf);
    u64 b1 = __ballot(v[k].y > tf);
    u64 b2 = __ballot(v[k].z > tf);
    u64 b3 = __ballot(v[k].w > tf);
    if ((lane & 15) == 0) {
      int sh = lane;             // 0,16,32,48
      u64 w = spread4(b0 >> sh) | (spread4(b1 >> sh) << 1)
            | (spread4(b2 >> sh) << 2) | (spread4(b3 >> sh) << 3);
      int base_word = ((g - lane) * 4) >> 6;
      pk[base_word + (lane >> 4)] = w;
    }
  }
}

// ---------------------------------------------------------------------------
// 7) fused dilate (H+V) on packed bits; OOB = 0 (clipped window).
// ---------------------------------------------------------------------------
__global__ void dilate_kernel(const u64* __restrict__ in, u64* __restrict__ out) {
  __shared__ u64 hm[68][16];
  int bx = blockIdx.x & 3;
  int by = blockIdx.x >> 2;
  int r0 = by * 64, c0 = bx * 16;
  int tid = threadIdx.x;
  for (int it = tid; it < 68 * 16; it += 256) {
    int rr = it >> 4;
    int cc = it & 15;
    int gy = r0 - 2 + rr;
    int gx = c0 + cc;
    u64 m = 0, l = 0, r = 0;
    if ((unsigned)gy < (unsigned)HH) {
      m = in[gy * WPR + gx];
      l = (gx > 0) ? in[gy * WPR + gx - 1] : 0ull;
      r = (gx < WPR - 1) ? in[gy * WPR + gx + 1] : 0ull;
    }
    hm[rr][cc] = m | (m << 1) | (m << 2) | (m >> 1) | (m >> 2)
                   | (l >> 62) | (l >> 63) | (r << 62) | (r << 63);
  }
  __syncthreads();
  for (int it = tid; it < 64 * 16; it += 256) {
    int rr = it >> 4;
    int cc = it & 15;
    u64 v = hm[rr][cc] | hm[rr + 1][cc] | hm[rr + 2][cc] | hm[rr + 3][cc] | hm[rr + 4][cc];
    out[(r0 + rr) * WPR + c0 + cc] = v;
  }
}

// ---------------------------------------------------------------------------
// 8) fused erode (De Morgan) + unpack to f32: out = 1 - bit(dilate(~d1)).
// ---------------------------------------------------------------------------
__global__ void erode_unpack_kernel(const u64* __restrict__ in, float* __restrict__ out) {
  __shared__ u64 hm[68][16];
  __shared__ u64 d2[64][16];
  int bx = blockIdx.x & 3;
  int by = blockIdx.x >> 2;
  int r0 = by * 64, c0 = bx * 16;
  int tid = threadIdx.x;
  for (int it = tid; it < 68 * 16; it += 256) {
    int rr = it >> 4;
    int cc = it & 15;
    int gy = r0 - 2 + rr;
    int gx = c0 + cc;
    u64 m = 0, l = 0, r = 0;
    if ((unsigned)gy < (unsigned)HH) {
      m = ~in[gy * WPR + gx];
      l = (gx > 0) ? ~in[gy * WPR + gx - 1] : 0ull;
      r = (gx < WPR - 1) ? ~in[gy * WPR + gx + 1] : 0ull;
    }
    hm[rr][cc] = m | (m << 1) | (m << 2) | (m >> 1) | (m >> 2)
                   | (l >> 62) | (l >> 63) | (r << 62) | (r << 63);
  }
  __syncthreads();
  for (int it = tid; it < 64 * 16; it += 256) {
    int rr = it >> 4;
    int cc = it & 15;
    d2[rr][cc] = hm[rr][cc] | hm[rr + 1][cc] | hm[rr + 2][cc] | hm[rr + 3][cc] | hm[rr + 4][cc];
  }
  __syncthreads();
  int colbase = c0 * 64;
  for (int it = tid; it < 64 * 256; it += 256) {
    int rr = it >> 8;
    int px0 = (it & 255) * 4;
    u64 w = d2[rr][px0 >> 6];
    int sh = px0 & 63;
    float4 o;
    o.x = (float)(1 - (int)((w >> (sh + 0)) & 1ull));
    o.y = (float)(1 - (int)((w >> (sh + 1)) & 1ull));
    o.z = (float)(1 - (int)((w >> (sh + 2)) & 1ull));
    o.w = (float)(1 - (int)((w >> (sh + 3)) & 1ull));
    *(float4*)(out + (size_t)(r0 + rr) * WW + colbase + px0) = o;
  }
}

// ---------------------------------------------------------------------------
extern "C" void kernel_launch(void* const* d_in, const int* in_sizes, int n_in,
                              void* d_out, int out_size, void* d_ws, size_t ws_size,
                              hipStream_t stream) {
  const float* x = (const float*)d_in[0];
  if (n_in > 1 && in_sizes[0] != NPIX) x = (const float*)d_in[1];
  float* out = (float*)d_out;
  char* ws = (char*)d_ws;

  // workspace layout — control block ~7.4 MB + 64 MB blur buffer at 8 MB.
  // hist and bandcnt are adjacent so one memset clears both.
  const size_t OFF_HIST = 0;          // 2,097,152
  const size_t OFF_BCNT = 2097152;    // 256
  const size_t OFF_TH   = 2097408;    // 256
  const size_t OFF_PKA  = 2097664;    // 2,097,152
  const size_t OFF_PKB  = 4194816;    // 2,097,152
  const size_t OFF_BINS = 6291968;    // 1,024
  const size_t OFF_VHL  = 6292992;    // 512
  const size_t OFF_BAND = 6293504;    // 1,048,576 (end ~7.34 MB)
  const size_t OFF_BLUR = 8388608;    // 64 MB blur image (normal cached mem)
  const size_t WS_NEED  = OFF_BLUR + (size_t)NPIX * sizeof(float);  // 72 MB
  uint32_t* hist    = (uint32_t*)(ws + OFF_HIST);
  uint32_t* bandcnt = (uint32_t*)(ws + OFF_BCNT);
  float*    th      = (float*)(ws + OFF_TH);
  u64*      PKA     = (u64*)(ws + OFF_PKA);
  u64*      PKB     = (u64*)(ws + OFF_PKB);
  int4*     bins4   = (int4*)(ws + OFF_BINS);
  float2*   vhl     = (float2*)(ws + OFF_VHL);
  float*    band    = (float*)(ws + OFF_BAND);

  // KEY CHANGE: keep the blurred image in d_ws (normal device memory).
  // d_out reads measured ~400 GB/s uncached-like across 3 structural load
  // variants; d_ws/d_in reads are fast. Fall back to d_out if ws too small.
  float* blurred = (ws_size >= WS_NEED) ? (float*)(ws + OFF_BLUR) : out;

  const int TPB = 256;
  const int NB16 = NPIX / 16 / TPB;   // 4096 blocks (16 px/thread kernels)

  // one memset covers hist (2 MB) + bandcnt (256 B), adjacent in ws
  hipMemsetAsync(hist, 0, (size_t)NFRAG * NBINS * sizeof(uint32_t) + NFRAG * sizeof(uint32_t), stream);
  blur_hist_kernel<<<1024, 512, 0, stream>>>(x, blurred, hist);
  findcrit_kernel<<<NFRAG, TPB, 0, stream>>>(hist, bins4);
  gather_kernel<<<NB16, TPB, 0, stream>>>(blurred, bins4, band, bandcnt);
  select_kernel<<<NFRAG, TPB, 0, stream>>>(band, bandcnt, bins4, vhl);
  walk_kernel<<<1, 64, 0, stream>>>(vhl, th);
  mask_pack_kernel<<<NB16, TPB, 0, stream>>>(blurred, th, PKA);
  dilate_kernel<<<256, TPB, 0, stream>>>(PKA, PKB);
  erode_unpack_kernel<<<256, TPB, 0, stream>>>(PKB, out);
}

// Round 6
// 260.157 us; speedup vs baseline: 1.2996x; 1.2122x over previous
//
#include <hip/hip_runtime.h>
#include <stdint.h>

#define HH 4096
#define WW 4096
#define NPIX (HH * WW)
#define NBINS 8192
#define NFRAG 64
#define FRAG_PIX (512 * 512)   // 2^18
#define WPR 64                 // u64 words per row (4096/64)
#define NWORDS (HH * WPR)      // 262144
#define CAP 4096               // per-fragment critical-band capacity
#define LCAP 2048              // per-block LDS match buffer

// Reference stop conditions (integer-exact):
//   phase0 stop: cnt >= 31458 <=> th < V_HI,  V_HI = v_sorted[230686]
//   phase1 stop: cnt <= 20971 <=> th >= V_LO, V_LO = v_sorted[241172]
#define RANK_HI 230686u
#define RANK_LO 241172u

typedef unsigned long long u64;

__device__ __forceinline__ int frag_of(int py, int px) {
  return ((py >> 9) << 3) + (px >> 9);
}

__device__ __forceinline__ int bin_of(float v) {
  int b = (int)(v * 8192.0f);   // monotone f32 map
  if (b < 0) b = 0;
  if (b > NBINS - 1) b = NBINS - 1;
  return b;
}

// spread 16 bits so bit i lands at position 4i
__device__ __forceinline__ u64 spread4(u64 x) {
  x &= 0xFFFFull;
  x = (x | (x << 24)) & 0x000000FF000000FFull;
  x = (x | (x << 12)) & 0x000F000F000F000Full;
  x = (x | (x << 6))  & 0x0303030303030303ull;
  x = (x | (x << 3))  & 0x1111111111111111ull;
  return x;
}

// ---------------------------------------------------------------------------
// VERIFIED bit-exact blur tree (numpy pairwise_sum n=25 over materialized
// (windows*k), row-major taps, OOB -> exact 0). DO NOT TOUCH.
// ---------------------------------------------------------------------------
__device__ __forceinline__ float blur_tree(const float rowbuf[5][8], int e) {
  const float K = (float)(1.0 / 25.0);
  float p[25];
#pragma unroll
  for (int i = 0; i < 25; ++i) {
    p[i] = __fmul_rn(rowbuf[i / 5][e + (i % 5)], K);
  }
  float r0 = __fadd_rn(__fadd_rn(p[0], p[8]),  p[16]);
  float r1 = __fadd_rn(__fadd_rn(p[1], p[9]),  p[17]);
  float r2 = __fadd_rn(__fadd_rn(p[2], p[10]), p[18]);
  float r3 = __fadd_rn(__fadd_rn(p[3], p[11]), p[19]);
  float r4 = __fadd_rn(__fadd_rn(p[4], p[12]), p[20]);
  float r5 = __fadd_rn(__fadd_rn(p[5], p[13]), p[21]);
  float r6 = __fadd_rn(__fadd_rn(p[6], p[14]), p[22]);
  float r7 = __fadd_rn(__fadd_rn(p[7], p[15]), p[23]);
  float res = __fadd_rn(
      __fadd_rn(__fadd_rn(r0, r1), __fadd_rn(r2, r3)),
      __fadd_rn(__fadd_rn(r4, r5), __fadd_rn(r6, r7)));
  return __fadd_rn(res, p[24]);
}

// ---------------------------------------------------------------------------
// 1) FUSED blur + per-fragment LDS histogram.
//    4x4 output patch per thread. Flush is STAGGERED: the 16 sibling blocks
//    of a fragment start their bin sweep 512 apart so same-address global
//    atomics never coincide (was ~2M lockstep atomics onto 8192 addrs).
// ---------------------------------------------------------------------------
__global__ void __launch_bounds__(512)
blur_hist_kernel(const float* __restrict__ x,
                 float* __restrict__ out,
                 uint32_t* __restrict__ hist) {
  __shared__ uint32_t lh[NBINS];
  int tid = threadIdx.x;
  for (int i = tid; i < NBINS; i += 512) lh[i] = 0;
  __syncthreads();
  int f = blockIdx.x >> 4;
  int s = blockIdx.x & 15;
  int row0 = (f >> 3) * 512 + s * 32;
  int col0 = (f & 7) * 512;
  // 8 patch-rows x 128 patch-cols per 32x512 slice; 512 threads -> 2 iters
  for (int it = tid; it < 8 * 128; it += 512) {
    int pr = it >> 7;          // patch row 0..7
    int c4 = it & 127;         // patch col 0..127
    int py = row0 + pr * 4;
    int px = col0 + c4 * 4;
    float rb[8][8];
    bool interior = (px >= 2) && (px + 5 < WW);
#pragma unroll
    for (int r = 0; r < 8; ++r) {
      int yy = py - 2 + r;
      if ((unsigned)yy >= (unsigned)HH) {
#pragma unroll
        for (int j = 0; j < 8; ++j) rb[r][j] = 0.0f;
      } else if (interior) {
        const float* rp = x + (size_t)yy * WW + px;
        float2 L = *(const float2*)(rp - 2);
        float4 M = *(const float4*)(rp);
        float2 R = *(const float2*)(rp + 4);
        rb[r][0] = L.x; rb[r][1] = L.y;
        rb[r][2] = M.x; rb[r][3] = M.y;
        rb[r][4] = M.z; rb[r][5] = M.w;
        rb[r][6] = R.x; rb[r][7] = R.y;
      } else {
#pragma unroll
        for (int j = 0; j < 8; ++j) {
          int xx = px - 2 + j;
          rb[r][j] = ((unsigned)xx < (unsigned)WW) ? x[(size_t)yy * WW + xx] : 0.0f;
        }
      }
    }
#pragma unroll
    for (int orow = 0; orow < 4; ++orow) {
      float4 res;
      res.x = blur_tree(rb + orow, 0);
      res.y = blur_tree(rb + orow, 1);
      res.z = blur_tree(rb + orow, 2);
      res.w = blur_tree(rb + orow, 3);
      *(float4*)(out + (size_t)(py + orow) * WW + px) = res;
      atomicAdd(&lh[bin_of(res.x)], 1u);
      atomicAdd(&lh[bin_of(res.y)], 1u);
      atomicAdd(&lh[bin_of(res.z)], 1u);
      atomicAdd(&lh[bin_of(res.w)], 1u);
    }
  }
  __syncthreads();
  uint32_t* hf = hist + f * NBINS;
  int start = ((s << 9) + tid) & (NBINS - 1);   // sibling-staggered sweep
  for (int ii = 0; ii < NBINS; ii += 512) {
    int i = (start + ii) & (NBINS - 1);
    uint32_t c = lh[i];
    if (c) atomicAdd(&hf[i], c);
  }
}

// ---------------------------------------------------------------------------
// 2) find critical buckets + local ranks. bins4[f] = (bhi, blo, khi, klo).
// ---------------------------------------------------------------------------
__global__ void findcrit_kernel(const uint32_t* __restrict__ hist,
                                int4* __restrict__ bins4) {
  __shared__ uint32_t segsum[256];
  __shared__ uint32_t segoff[256];
  __shared__ int4 result;
  int f = blockIdx.x;
  int tid = threadIdx.x;
  const uint32_t* hf = hist + f * NBINS;
  int base = tid * 32;
  uint32_t h32[32];
  uint32_t s = 0;
  for (int i = 0; i < 32; ++i) { h32[i] = hf[base + i]; s += h32[i]; }
  segsum[tid] = s;
  __syncthreads();
  if (tid == 0) {
    uint32_t a = 0;
    for (int i = 0; i < 256; ++i) { segoff[i] = a; a += segsum[i]; }
  }
  __syncthreads();
  uint32_t st = segoff[tid];
  uint32_t en = st + segsum[tid];
  if (st <= RANK_HI && RANK_HI < en) {
    uint32_t a = st;
    for (int i = 0; i < 32; ++i) {
      uint32_t nx = a + h32[i];
      if (RANK_HI < nx) { result.x = base + i; result.z = (int)(RANK_HI - a); break; }
      a = nx;
    }
  }
  if (st <= RANK_LO && RANK_LO < en) {
    uint32_t a = st;
    for (int i = 0; i < 32; ++i) {
      uint32_t nx = a + h32[i];
      if (RANK_LO < nx) { result.y = base + i; result.w = (int)(RANK_LO - a); break; }
      a = nx;
    }
  }
  __syncthreads();
  if (tid == 0) bins4[f] = result;
}

// ---------------------------------------------------------------------------
// 3) gather — ATOMIC-PRIVATIZED. Fragment-aligned blocks (64 frags x 16
//    slices), matches collected in LDS via LDS atomics, ONE global
//    atomicAdd per block reserves the range, then plain stores. Global
//    same-address atomics drop ~14K -> 1K (value-returning hot-line
//    atomics across 8 XCDs were the dependent-chain stall). Band order
//    changes; select is order-independent exact rank -> bit-exact.
// ---------------------------------------------------------------------------
__global__ void __launch_bounds__(256)
gather_kernel(const float* __restrict__ blur,
              const int4* __restrict__ bins4,
              float* __restrict__ band,
              uint32_t* __restrict__ bandcnt) {
  __shared__ float lval[LCAP];
  __shared__ uint32_t lcnt;
  __shared__ uint32_t gbase;
  int f = blockIdx.x >> 4;
  int s = blockIdx.x & 15;
  int tid = threadIdx.x;
  if (tid == 0) lcnt = 0;
  __syncthreads();
  int row0 = (f >> 3) * 512 + s * 32;
  int col0 = (f & 7) * 512;
  int4 info = bins4[f];
  // 32 rows x 128 float4 = 4096 f4 per slice; 256 threads -> 16 each
  for (int it = tid; it < 32 * 128; it += 256) {
    int rr = it >> 7, c4 = it & 127;
    float4 v = *(const float4*)(blur + (size_t)(row0 + rr) * WW + col0 + c4 * 4);
    float vv[4] = {v.x, v.y, v.z, v.w};
#pragma unroll
    for (int e = 0; e < 4; ++e) {
      int b = bin_of(vv[e]);
      if (b == info.x || b == info.y) {
        uint32_t p = atomicAdd(&lcnt, 1u);
        if (p < LCAP) lval[p] = vv[e];
        else {   // overflow fallback (never for expected data)
          uint32_t pos = atomicAdd(&bandcnt[f], 1u);
          if (pos < CAP) band[(size_t)f * CAP + pos] = vv[e];
        }
      }
    }
  }
  __syncthreads();
  uint32_t n = lcnt < LCAP ? lcnt : LCAP;
  if (tid == 0) gbase = atomicAdd(&bandcnt[f], n);
  __syncthreads();
  uint32_t base = gbase;
  for (uint32_t i = tid; i < n; i += 256) {
    uint32_t pos = base + i;
    if (pos < CAP) band[(size_t)f * CAP + pos] = lval[i];
  }
}

// ---------------------------------------------------------------------------
// 4) exact order-statistic selection within the critical buckets
// ---------------------------------------------------------------------------
__global__ void select_kernel(const float* __restrict__ band,
                              const uint32_t* __restrict__ bandcnt,
                              const int4* __restrict__ bins4,
                              float2* __restrict__ vhl) {
  __shared__ float wv[CAP];
  __shared__ float res[2];
  int f = blockIdx.x;
  int tid = threadIdx.x;
  int n = (int)bandcnt[f];
  if (n > CAP) n = CAP;
  for (int i = tid; i < n; i += 256) wv[i] = band[(size_t)f * CAP + i];
  __syncthreads();
  int4 info = bins4[f];
#pragma unroll
  for (int sel = 0; sel < 2; ++sel) {
    int tb = sel ? info.y : info.x;
    int k  = sel ? info.w : info.z;
    for (int i = tid; i < n; i += 256) {
      float w = wv[i];
      if (bin_of(w) != tb) continue;
      int less = 0, leq = 0;
      for (int j = 0; j < n; ++j) {
        float u = wv[j];
        if (bin_of(u) == tb) {
          less += (u < w) ? 1 : 0;
          leq  += (u <= w) ? 1 : 0;
        }
      }
      if (less <= k && k < leq) res[sel] = w;   // unique value; benign race
    }
  }
  __syncthreads();
  if (tid == 0) vhl[f] = make_float2(res[0], res[1]);
}

// ---------------------------------------------------------------------------
// 5) threshold walk — branchless predicated steps (16 per exit check).
//    Each conditional step is EXACTLY the reference's while-iteration:
//    taken  -> th = __fadd_rn(th, ±step) ; not-taken -> no-op.
// ---------------------------------------------------------------------------
__global__ void walk_kernel(const float2* __restrict__ vhl, float* __restrict__ th_out) {
  int lane = threadIdx.x;
  float2 mine = vhl[lane];   // lane f holds fragment f's (V_HI, V_LO)
  float th = 0.5f;           // TH1_INIT
  for (int f = 0; f < NFRAG; ++f) {
    float VH = __shfl(mine.x, f);
    float VL = __shfl(mine.y, f);
    // phase 0: while th >= VH: th -= 0.0005
    while (th >= VH) {
#pragma unroll
      for (int i = 0; i < 16; ++i) {
        float t2 = __fadd_rn(th, -0.0005f);
        th = (th >= VH) ? t2 : th;
      }
    }
    // phase 1: while th < VL: th += 0.0005
    while (th < VL) {
#pragma unroll
      for (int i = 0; i < 16; ++i) {
        float t2 = __fadd_rn(th, 0.0005f);
        th = (th < VL) ? t2 : th;
      }
    }
    if (lane == 0) th_out[f] = th;
  }
}

// ---------------------------------------------------------------------------
// 6) mask + bit-pack — 16 px/thread, 4 float4 loads, ballot interleave.
// ---------------------------------------------------------------------------
__global__ void __launch_bounds__(256)
mask_pack_kernel(const float* __restrict__ blur,
                 const float* __restrict__ th,
                 u64* __restrict__ pk) {
  const int T = NPIX / 16;   // 1,048,576 threads
  int t = blockIdx.x * blockDim.x + threadIdx.x;
  float4 v[4];
#pragma unroll
  for (int k = 0; k < 4; ++k) {
    v[k] = *(const float4*)(blur + (size_t)(t + k * T) * 4);
  }
  int lane = threadIdx.x & 63;
#pragma unroll
  for (int k = 0; k < 4; ++k) {
    int g = t + k * T;           // 4-px group index
    int p0 = g * 4;
    float tf = th[frag_of(p0 >> 12, p0 & (WW - 1))];
    u64 b0 = __ballot(v[k].x > tf);
    u64 b1 = __ballot(v[k].y > tf);
    u64 b2 = __ballot(v[k].z > tf);
    u64 b3 = __ballot(v[k].w > tf);
    if ((lane & 15) == 0) {
      int sh = lane;             // 0,16,32,48
      u64 w = spread4(b0 >> sh) | (spread4(b1 >> sh) << 1)
            | (spread4(b2 >> sh) << 2) | (spread4(b3 >> sh) << 3);
      int base_word = ((g - lane) * 4) >> 6;
      pk[base_word + (lane >> 4)] = w;
    }
  }
}

// ---------------------------------------------------------------------------
// 7) fused dilate (H+V) on packed bits; OOB = 0 (clipped window).
// ---------------------------------------------------------------------------
__global__ void dilate_kernel(const u64* __restrict__ in, u64* __restrict__ out) {
  __shared__ u64 hm[68][16];
  int bx = blockIdx.x & 3;
  int by = blockIdx.x >> 2;
  int r0 = by * 64, c0 = bx * 16;
  int tid = threadIdx.x;
  for (int it = tid; it < 68 * 16; it += 256) {
    int rr = it >> 4;
    int cc = it & 15;
    int gy = r0 - 2 + rr;
    int gx = c0 + cc;
    u64 m = 0, l = 0, r = 0;
    if ((unsigned)gy < (unsigned)HH) {
      m = in[gy * WPR + gx];
      l = (gx > 0) ? in[gy * WPR + gx - 1] : 0ull;
      r = (gx < WPR - 1) ? in[gy * WPR + gx + 1] : 0ull;
    }
    hm[rr][cc] = m | (m << 1) | (m << 2) | (m >> 1) | (m >> 2)
                   | (l >> 62) | (l >> 63) | (r << 62) | (r << 63);
  }
  __syncthreads();
  for (int it = tid; it < 64 * 16; it += 256) {
    int rr = it >> 4;
    int cc = it & 15;
    u64 v = hm[rr][cc] | hm[rr + 1][cc] | hm[rr + 2][cc] | hm[rr + 3][cc] | hm[rr + 4][cc];
    out[(r0 + rr) * WPR + c0 + cc] = v;
  }
}

// ---------------------------------------------------------------------------
// 8) fused erode (De Morgan) + unpack to f32: out = 1 - bit(dilate(~d1)).
// ---------------------------------------------------------------------------
__global__ void erode_unpack_kernel(const u64* __restrict__ in, float* __restrict__ out) {
  __shared__ u64 hm[68][16];
  __shared__ u64 d2[64][16];
  int bx = blockIdx.x & 3;
  int by = blockIdx.x >> 2;
  int r0 = by * 64, c0 = bx * 16;
  int tid = threadIdx.x;
  for (int it = tid; it < 68 * 16; it += 256) {
    int rr = it >> 4;
    int cc = it & 15;
    int gy = r0 - 2 + rr;
    int gx = c0 + cc;
    u64 m = 0, l = 0, r = 0;
    if ((unsigned)gy < (unsigned)HH) {
      m = ~in[gy * WPR + gx];
      l = (gx > 0) ? ~in[gy * WPR + gx - 1] : 0ull;
      r = (gx < WPR - 1) ? ~in[gy * WPR + gx + 1] : 0ull;
    }
    hm[rr][cc] = m | (m << 1) | (m << 2) | (m >> 1) | (m >> 2)
                   | (l >> 62) | (l >> 63) | (r << 62) | (r << 63);
  }
  __syncthreads();
  for (int it = tid; it < 64 * 16; it += 256) {
    int rr = it >> 4;
    int cc = it & 15;
    d2[rr][cc] = hm[rr][cc] | hm[rr + 1][cc] | hm[rr + 2][cc] | hm[rr + 3][cc] | hm[rr + 4][cc];
  }
  __syncthreads();
  int colbase = c0 * 64;
  for (int it = tid; it < 64 * 256; it += 256) {
    int rr = it >> 8;
    int px0 = (it & 255) * 4;
    u64 w = d2[rr][px0 >> 6];
    int sh = px0 & 63;
    float4 o;
    o.x = (float)(1 - (int)((w >> (sh + 0)) & 1ull));
    o.y = (float)(1 - (int)((w >> (sh + 1)) & 1ull));
    o.z = (float)(1 - (int)((w >> (sh + 2)) & 1ull));
    o.w = (float)(1 - (int)((w >> (sh + 3)) & 1ull));
    *(float4*)(out + (size_t)(r0 + rr) * WW + colbase + px0) = o;
  }
}

// ---------------------------------------------------------------------------
extern "C" void kernel_launch(void* const* d_in, const int* in_sizes, int n_in,
                              void* d_out, int out_size, void* d_ws, size_t ws_size,
                              hipStream_t stream) {
  const float* x = (const float*)d_in[0];
  if (n_in > 1 && in_sizes[0] != NPIX) x = (const float*)d_in[1];
  float* out = (float*)d_out;
  char* ws = (char*)d_ws;

  // workspace layout — control block ~7.4 MB + 64 MB blur buffer at 8 MB.
  // hist and bandcnt are adjacent so one memset clears both.
  const size_t OFF_HIST = 0;          // 2,097,152
  const size_t OFF_BCNT = 2097152;    // 256
  const size_t OFF_TH   = 2097408;    // 256
  const size_t OFF_PKA  = 2097664;    // 2,097,152
  const size_t OFF_PKB  = 4194816;    // 2,097,152
  const size_t OFF_BINS = 6291968;    // 1,024
  const size_t OFF_VHL  = 6292992;    // 512
  const size_t OFF_BAND = 6293504;    // 1,048,576 (end ~7.34 MB)
  const size_t OFF_BLUR = 8388608;    // 64 MB blur image
  const size_t WS_NEED  = OFF_BLUR + (size_t)NPIX * sizeof(float);  // 72 MB
  uint32_t* hist    = (uint32_t*)(ws + OFF_HIST);
  uint32_t* bandcnt = (uint32_t*)(ws + OFF_BCNT);
  float*    th      = (float*)(ws + OFF_TH);
  u64*      PKA     = (u64*)(ws + OFF_PKA);
  u64*      PKB     = (u64*)(ws + OFF_PKB);
  int4*     bins4   = (int4*)(ws + OFF_BINS);
  float2*   vhl     = (float2*)(ws + OFF_VHL);
  float*    band    = (float*)(ws + OFF_BAND);

  float* blurred = (ws_size >= WS_NEED) ? (float*)(ws + OFF_BLUR) : out;

  const int TPB = 256;
  const int NB16 = NPIX / 16 / TPB;   // 4096 blocks (mask_pack)

  // one memset covers hist (2 MB) + bandcnt (256 B), adjacent in ws
  hipMemsetAsync(hist, 0, (size_t)NFRAG * NBINS * sizeof(uint32_t) + NFRAG * sizeof(uint32_t), stream);
  blur_hist_kernel<<<1024, 512, 0, stream>>>(x, blurred, hist);
  findcrit_kernel<<<NFRAG, TPB, 0, stream>>>(hist, bins4);
  gather_kernel<<<1024, TPB, 0, stream>>>(blurred, bins4, band, bandcnt);
  select_kernel<<<NFRAG, TPB, 0, stream>>>(band, bandcnt, bins4, vhl);
  walk_kernel<<<1, 64, 0, stream>>>(vhl, th);
  mask_pack_kernel<<<NB16, TPB, 0, stream>>>(blurred, th, PKA);
  dilate_kernel<<<256, TPB, 0, stream>>>(PKA, PKB);
  erode_unpack_kernel<<<256, TPB, 0, stream>>>(PKB, out);
}

// Round 7
// 253.902 us; speedup vs baseline: 1.3317x; 1.0246x over previous
//
#include <hip/hip_runtime.h>
#include <stdint.h>

#define HH 4096
#define WW 4096
#define NPIX (HH * WW)
#define NBINS 8192
#define NFRAG 64
#define FRAG_PIX (512 * 512)   // 2^18
#define WPR 64                 // u64 words per row (4096/64)
#define NWORDS (HH * WPR)      // 262144
#define CAP 4096               // per-fragment critical-band capacity
#define LCAP 2048              // per-block LDS match buffer

// Reference stop conditions (integer-exact):
//   phase0 stop: cnt >= 31458 <=> th < V_HI,  V_HI = v_sorted[230686]
//   phase1 stop: cnt <= 20971 <=> th >= V_LO, V_LO = v_sorted[241172]
#define RANK_HI 230686u
#define RANK_LO 241172u

typedef unsigned long long u64;

__device__ __forceinline__ int frag_of(int py, int px) {
  return ((py >> 9) << 3) + (px >> 9);
}

__device__ __forceinline__ int bin_of(float v) {
  int b = (int)(v * 8192.0f);   // monotone f32 map
  if (b < 0) b = 0;
  if (b > NBINS - 1) b = NBINS - 1;
  return b;
}

// spread 16 bits so bit i lands at position 4i
__device__ __forceinline__ u64 spread4(u64 x) {
  x &= 0xFFFFull;
  x = (x | (x << 24)) & 0x000000FF000000FFull;
  x = (x | (x << 12)) & 0x000F000F000F000Full;
  x = (x | (x << 6))  & 0x0303030303030303ull;
  x = (x | (x << 3))  & 0x1111111111111111ull;
  return x;
}

// ---------------------------------------------------------------------------
// VERIFIED bit-exact blur tree (numpy pairwise_sum n=25 over materialized
// (windows*k), row-major taps, OOB -> exact 0). DO NOT TOUCH.
// ---------------------------------------------------------------------------
__device__ __forceinline__ float blur_tree(const float rowbuf[5][8], int e) {
  const float K = (float)(1.0 / 25.0);
  float p[25];
#pragma unroll
  for (int i = 0; i < 25; ++i) {
    p[i] = __fmul_rn(rowbuf[i / 5][e + (i % 5)], K);
  }
  float r0 = __fadd_rn(__fadd_rn(p[0], p[8]),  p[16]);
  float r1 = __fadd_rn(__fadd_rn(p[1], p[9]),  p[17]);
  float r2 = __fadd_rn(__fadd_rn(p[2], p[10]), p[18]);
  float r3 = __fadd_rn(__fadd_rn(p[3], p[11]), p[19]);
  float r4 = __fadd_rn(__fadd_rn(p[4], p[12]), p[20]);
  float r5 = __fadd_rn(__fadd_rn(p[5], p[13]), p[21]);
  float r6 = __fadd_rn(__fadd_rn(p[6], p[14]), p[22]);
  float r7 = __fadd_rn(__fadd_rn(p[7], p[15]), p[23]);
  float res = __fadd_rn(
      __fadd_rn(__fadd_rn(r0, r1), __fadd_rn(r2, r3)),
      __fadd_rn(__fadd_rn(r4, r5), __fadd_rn(r6, r7)));
  return __fadd_rn(res, p[24]);
}

// ---------------------------------------------------------------------------
// 1) FUSED blur + per-fragment LDS histogram (staggered flush).
// ---------------------------------------------------------------------------
__global__ void __launch_bounds__(512)
blur_hist_kernel(const float* __restrict__ x,
                 float* __restrict__ out,
                 uint32_t* __restrict__ hist) {
  __shared__ uint32_t lh[NBINS];
  int tid = threadIdx.x;
  for (int i = tid; i < NBINS; i += 512) lh[i] = 0;
  __syncthreads();
  int f = blockIdx.x >> 4;
  int s = blockIdx.x & 15;
  int row0 = (f >> 3) * 512 + s * 32;
  int col0 = (f & 7) * 512;
  // 8 patch-rows x 128 patch-cols per 32x512 slice; 512 threads -> 2 iters
  for (int it = tid; it < 8 * 128; it += 512) {
    int pr = it >> 7;          // patch row 0..7
    int c4 = it & 127;         // patch col 0..127
    int py = row0 + pr * 4;
    int px = col0 + c4 * 4;
    float rb[8][8];
    bool interior = (px >= 2) && (px + 5 < WW);
#pragma unroll
    for (int r = 0; r < 8; ++r) {
      int yy = py - 2 + r;
      if ((unsigned)yy >= (unsigned)HH) {
#pragma unroll
        for (int j = 0; j < 8; ++j) rb[r][j] = 0.0f;
      } else if (interior) {
        const float* rp = x + (size_t)yy * WW + px;
        float2 L = *(const float2*)(rp - 2);
        float4 M = *(const float4*)(rp);
        float2 R = *(const float2*)(rp + 4);
        rb[r][0] = L.x; rb[r][1] = L.y;
        rb[r][2] = M.x; rb[r][3] = M.y;
        rb[r][4] = M.z; rb[r][5] = M.w;
        rb[r][6] = R.x; rb[r][7] = R.y;
      } else {
#pragma unroll
        for (int j = 0; j < 8; ++j) {
          int xx = px - 2 + j;
          rb[r][j] = ((unsigned)xx < (unsigned)WW) ? x[(size_t)yy * WW + xx] : 0.0f;
        }
      }
    }
#pragma unroll
    for (int orow = 0; orow < 4; ++orow) {
      float4 res;
      res.x = blur_tree(rb + orow, 0);
      res.y = blur_tree(rb + orow, 1);
      res.z = blur_tree(rb + orow, 2);
      res.w = blur_tree(rb + orow, 3);
      *(float4*)(out + (size_t)(py + orow) * WW + px) = res;
      atomicAdd(&lh[bin_of(res.x)], 1u);
      atomicAdd(&lh[bin_of(res.y)], 1u);
      atomicAdd(&lh[bin_of(res.z)], 1u);
      atomicAdd(&lh[bin_of(res.w)], 1u);
    }
  }
  __syncthreads();
  uint32_t* hf = hist + f * NBINS;
  int start = ((s << 9) + tid) & (NBINS - 1);   // sibling-staggered sweep
  for (int ii = 0; ii < NBINS; ii += 512) {
    int i = (start + ii) & (NBINS - 1);
    uint32_t c = lh[i];
    if (c) atomicAdd(&hf[i], c);
  }
}

// ---------------------------------------------------------------------------
// 2) find critical buckets + local ranks. bins4[f] = (bhi, blo, khi, klo).
// ---------------------------------------------------------------------------
__global__ void findcrit_kernel(const uint32_t* __restrict__ hist,
                                int4* __restrict__ bins4) {
  __shared__ uint32_t segsum[256];
  __shared__ uint32_t segoff[256];
  __shared__ int4 result;
  int f = blockIdx.x;
  int tid = threadIdx.x;
  const uint32_t* hf = hist + f * NBINS;
  int base = tid * 32;
  uint32_t h32[32];
  uint32_t s = 0;
  for (int i = 0; i < 32; ++i) { h32[i] = hf[base + i]; s += h32[i]; }
  segsum[tid] = s;
  __syncthreads();
  if (tid == 0) {
    uint32_t a = 0;
    for (int i = 0; i < 256; ++i) { segoff[i] = a; a += segsum[i]; }
  }
  __syncthreads();
  uint32_t st = segoff[tid];
  uint32_t en = st + segsum[tid];
  if (st <= RANK_HI && RANK_HI < en) {
    uint32_t a = st;
    for (int i = 0; i < 32; ++i) {
      uint32_t nx = a + h32[i];
      if (RANK_HI < nx) { result.x = base + i; result.z = (int)(RANK_HI - a); break; }
      a = nx;
    }
  }
  if (st <= RANK_LO && RANK_LO < en) {
    uint32_t a = st;
    for (int i = 0; i < 32; ++i) {
      uint32_t nx = a + h32[i];
      if (RANK_LO < nx) { result.y = base + i; result.w = (int)(RANK_LO - a); break; }
      a = nx;
    }
  }
  __syncthreads();
  if (tid == 0) bins4[f] = result;
}

// ---------------------------------------------------------------------------
// 3) gather — atomic-privatized (R6, verified). LDS collect + one global
//    atomicAdd per block. Order-independent select makes this bit-exact.
// ---------------------------------------------------------------------------
__global__ void __launch_bounds__(256)
gather_kernel(const float* __restrict__ blur,
              const int4* __restrict__ bins4,
              float* __restrict__ band,
              uint32_t* __restrict__ bandcnt) {
  __shared__ float lval[LCAP];
  __shared__ uint32_t lcnt;
  __shared__ uint32_t gbase;
  int f = blockIdx.x >> 4;
  int s = blockIdx.x & 15;
  int tid = threadIdx.x;
  if (tid == 0) lcnt = 0;
  __syncthreads();
  int row0 = (f >> 3) * 512 + s * 32;
  int col0 = (f & 7) * 512;
  int4 info = bins4[f];
  for (int it = tid; it < 32 * 128; it += 256) {
    int rr = it >> 7, c4 = it & 127;
    float4 v = *(const float4*)(blur + (size_t)(row0 + rr) * WW + col0 + c4 * 4);
    float vv[4] = {v.x, v.y, v.z, v.w};
#pragma unroll
    for (int e = 0; e < 4; ++e) {
      int b = bin_of(vv[e]);
      if (b == info.x || b == info.y) {
        uint32_t p = atomicAdd(&lcnt, 1u);
        if (p < LCAP) lval[p] = vv[e];
        else {   // overflow fallback (never for expected data)
          uint32_t pos = atomicAdd(&bandcnt[f], 1u);
          if (pos < CAP) band[(size_t)f * CAP + pos] = vv[e];
        }
      }
    }
  }
  __syncthreads();
  uint32_t n = lcnt < LCAP ? lcnt : LCAP;
  if (tid == 0) gbase = atomicAdd(&bandcnt[f], n);
  __syncthreads();
  uint32_t base = gbase;
  for (uint32_t i = tid; i < n; i += 256) {
    uint32_t pos = base + i;
    if (pos < CAP) band[(size_t)f * CAP + pos] = lval[i];
  }
}

// ---------------------------------------------------------------------------
// 4) exact order-statistic selection within the critical buckets
// ---------------------------------------------------------------------------
__global__ void select_kernel(const float* __restrict__ band,
                              const uint32_t* __restrict__ bandcnt,
                              const int4* __restrict__ bins4,
                              float2* __restrict__ vhl) {
  __shared__ float wv[CAP];
  __shared__ float res[2];
  int f = blockIdx.x;
  int tid = threadIdx.x;
  int n = (int)bandcnt[f];
  if (n > CAP) n = CAP;
  for (int i = tid; i < n; i += 256) wv[i] = band[(size_t)f * CAP + i];
  __syncthreads();
  int4 info = bins4[f];
#pragma unroll
  for (int sel = 0; sel < 2; ++sel) {
    int tb = sel ? info.y : info.x;
    int k  = sel ? info.w : info.z;
    for (int i = tid; i < n; i += 256) {
      float w = wv[i];
      if (bin_of(w) != tb) continue;
      int less = 0, leq = 0;
      for (int j = 0; j < n; ++j) {
        float u = wv[j];
        if (bin_of(u) == tb) {
          less += (u < w) ? 1 : 0;
          leq  += (u <= w) ? 1 : 0;
        }
      }
      if (less <= k && k < leq) res[sel] = w;   // unique value; benign race
    }
  }
  __syncthreads();
  if (tid == 0) vhl[f] = make_float2(res[0], res[1]);
}

// ---------------------------------------------------------------------------
// 5) threshold walk — branchless predicated steps (16 per exit check).
// ---------------------------------------------------------------------------
__global__ void walk_kernel(const float2* __restrict__ vhl, float* __restrict__ th_out) {
  int lane = threadIdx.x;
  float2 mine = vhl[lane];   // lane f holds fragment f's (V_HI, V_LO)
  float th = 0.5f;           // TH1_INIT
  for (int f = 0; f < NFRAG; ++f) {
    float VH = __shfl(mine.x, f);
    float VL = __shfl(mine.y, f);
    // phase 0: while th >= VH: th -= 0.0005
    while (th >= VH) {
#pragma unroll
      for (int i = 0; i < 16; ++i) {
        float t2 = __fadd_rn(th, -0.0005f);
        th = (th >= VH) ? t2 : th;
      }
    }
    // phase 1: while th < VL: th += 0.0005
    while (th < VL) {
#pragma unroll
      for (int i = 0; i < 16; ++i) {
        float t2 = __fadd_rn(th, 0.0005f);
        th = (th < VL) ? t2 : th;
      }
    }
    if (lane == 0) th_out[f] = th;
  }
}

// ---------------------------------------------------------------------------
// 6) mask + bit-pack — fragment-slice blocks (gather's proven shape):
//    th[f] is ONE wave-uniform scalar per block (was a per-group gather),
//    16-iteration strided float4 loop. Ballot word mapping unchanged:
//    wave covers 256 consecutive 64-aligned px, (g - lane) is the wave base.
// ---------------------------------------------------------------------------
__global__ void __launch_bounds__(256)
mask_pack_kernel(const float* __restrict__ blur,
                 const float* __restrict__ th,
                 u64* __restrict__ pk) {
  int f = blockIdx.x >> 4;
  int s = blockIdx.x & 15;
  int tid = threadIdx.x;
  int lane = tid & 63;
  int row0 = (f >> 3) * 512 + s * 32;
  int col0 = (f & 7) * 512;
  float tf = th[f];
  for (int it = tid; it < 32 * 128; it += 256) {
    int rr = it >> 7, c4 = it & 127;
    float4 v = *(const float4*)(blur + (size_t)(row0 + rr) * WW + col0 + c4 * 4);
    int g = ((row0 + rr) << 10) + (col0 >> 2) + c4;   // global 4-px group
    u64 b0 = __ballot(v.x > tf);
    u64 b1 = __ballot(v.y > tf);
    u64 b2 = __ballot(v.z > tf);
    u64 b3 = __ballot(v.w > tf);
    if ((lane & 15) == 0) {
      int sh = lane;             // 0,16,32,48
      u64 w = spread4(b0 >> sh) | (spread4(b1 >> sh) << 1)
            | (spread4(b2 >> sh) << 2) | (spread4(b3 >> sh) << 3);
      int base_word = ((g - lane) * 4) >> 6;
      pk[base_word + (lane >> 4)] = w;
    }
  }
}

// ---------------------------------------------------------------------------
// 7) FUSED morphology: dilate then erode (De Morgan) + unpack, one kernel.
//    16-row x 16-word tiles (1024 blocks). Stage A: d1 = dilate(PKA) over a
//    (+4 row, +2 word) halo, OOB = 0 (clipped). Stage B: n = valid ? ~d1 : 0
//    (exactly the old erode's OOB rule), dilate(n), out = 1 - bit.
// ---------------------------------------------------------------------------
__global__ void __launch_bounds__(256)
morph_kernel(const u64* __restrict__ in, float* __restrict__ out) {
  __shared__ u64 pkin[24][20];   // rows R0-4..R0+19, words W0-2..W0+17
  __shared__ u64 hA[24][20];     // horizontal dilate of pkin (j in 1..18)
  __shared__ u64 nD[20][20];     // valid ? ~d1 : 0   (rows R0-2.., j in 1..18)
  __shared__ u64 hB[20][20];     // horizontal dilate of nD (j in 2..17)
  int bx = blockIdx.x & 3;
  int by = blockIdx.x >> 2;
  int R0 = by * 16, W0 = bx * 16;
  int tid = threadIdx.x;
  for (int it = tid; it < 24 * 20; it += 256) {
    int i = it / 20, j = it % 20;
    int gy = R0 - 4 + i, gx = W0 - 2 + j;
    u64 m = 0;
    if ((unsigned)gy < (unsigned)HH && (unsigned)gx < (unsigned)WPR)
      m = in[gy * WPR + gx];
    pkin[i][j] = m;
  }
  __syncthreads();
  for (int it = tid; it < 24 * 18; it += 256) {
    int i = it / 18, j = 1 + it % 18;
    u64 m = pkin[i][j], l = pkin[i][j - 1], r = pkin[i][j + 1];
    hA[i][j] = m | (m << 1) | (m << 2) | (m >> 1) | (m >> 2)
                 | (l >> 62) | (l >> 63) | (r << 62) | (r << 63);
  }
  __syncthreads();
  for (int it = tid; it < 20 * 18; it += 256) {
    int i = it / 18, j = 1 + it % 18;
    u64 v = hA[i][j] | hA[i + 1][j] | hA[i + 2][j] | hA[i + 3][j] | hA[i + 4][j];
    int gy = R0 - 2 + i, gx = W0 - 2 + j;
    nD[i][j] = ((unsigned)gy < (unsigned)HH && (unsigned)gx < (unsigned)WPR)
                   ? ~v : 0ull;
  }
  __syncthreads();
  for (int it = tid; it < 20 * 16; it += 256) {
    int i = it / 16, j = 2 + it % 16;
    u64 m = nD[i][j], l = nD[i][j - 1], r = nD[i][j + 1];
    hB[i][j] = m | (m << 1) | (m << 2) | (m >> 1) | (m >> 2)
                 | (l >> 62) | (l >> 63) | (r << 62) | (r << 63);
  }
  __syncthreads();
  int colbase = W0 * 64;
  for (int it = tid; it < 16 * 256; it += 256) {
    int o = it >> 8;           // output row 0..15
    int px0 = (it & 255) * 4;  // col within the 1024-px tile
    int j = 2 + (px0 >> 6);
    u64 v = hB[o][j] | hB[o + 1][j] | hB[o + 2][j] | hB[o + 3][j] | hB[o + 4][j];
    int sh = px0 & 63;
    float4 ov;
    ov.x = (float)(1 - (int)((v >> (sh + 0)) & 1ull));
    ov.y = (float)(1 - (int)((v >> (sh + 1)) & 1ull));
    ov.z = (float)(1 - (int)((v >> (sh + 2)) & 1ull));
    ov.w = (float)(1 - (int)((v >> (sh + 3)) & 1ull));
    *(float4*)(out + (size_t)(R0 + o) * WW + colbase + px0) = ov;
  }
}

// ---------------------------------------------------------------------------
extern "C" void kernel_launch(void* const* d_in, const int* in_sizes, int n_in,
                              void* d_out, int out_size, void* d_ws, size_t ws_size,
                              hipStream_t stream) {
  const float* x = (const float*)d_in[0];
  if (n_in > 1 && in_sizes[0] != NPIX) x = (const float*)d_in[1];
  float* out = (float*)d_out;
  char* ws = (char*)d_ws;

  const size_t OFF_HIST = 0;          // 2,097,152
  const size_t OFF_BCNT = 2097152;    // 256
  const size_t OFF_TH   = 2097408;    // 256
  const size_t OFF_PKA  = 2097664;    // 2,097,152
  const size_t OFF_PKB  = 4194816;    // 2,097,152 (unused after fusion)
  const size_t OFF_BINS = 6291968;    // 1,024
  const size_t OFF_VHL  = 6292992;    // 512
  const size_t OFF_BAND = 6293504;    // 1,048,576
  const size_t OFF_BLUR = 8388608;    // 64 MB blur image
  const size_t WS_NEED  = OFF_BLUR + (size_t)NPIX * sizeof(float);  // 72 MB
  uint32_t* hist    = (uint32_t*)(ws + OFF_HIST);
  uint32_t* bandcnt = (uint32_t*)(ws + OFF_BCNT);
  float*    th      = (float*)(ws + OFF_TH);
  u64*      PKA     = (u64*)(ws + OFF_PKA);
  int4*     bins4   = (int4*)(ws + OFF_BINS);
  float2*   vhl     = (float2*)(ws + OFF_VHL);
  float*    band    = (float*)(ws + OFF_BAND);
  (void)OFF_PKB;

  float* blurred = (ws_size >= WS_NEED) ? (float*)(ws + OFF_BLUR) : out;

  const int TPB = 256;

  // one memset covers hist (2 MB) + bandcnt (256 B), adjacent in ws
  hipMemsetAsync(hist, 0, (size_t)NFRAG * NBINS * sizeof(uint32_t) + NFRAG * sizeof(uint32_t), stream);
  blur_hist_kernel<<<1024, 512, 0, stream>>>(x, blurred, hist);
  findcrit_kernel<<<NFRAG, TPB, 0, stream>>>(hist, bins4);
  gather_kernel<<<1024, TPB, 0, stream>>>(blurred, bins4, band, bandcnt);
  select_kernel<<<NFRAG, TPB, 0, stream>>>(band, bandcnt, bins4, vhl);
  walk_kernel<<<1, 64, 0, stream>>>(vhl, th);
  mask_pack_kernel<<<1024, TPB, 0, stream>>>(blurred, th, PKA);
  morph_kernel<<<1024, TPB, 0, stream>>>(PKA, out);
}